// Round 10
// baseline (663.347 us; speedup 1.0000x reference)
//
#include <hip/hip_runtime.h>
#include <math.h>

#define NPG    256
#define EPG    4096
#define NGRAPH 1024
#define NATTR  100000

// ---------------- LDS layout (bytes), total 76,960 ----------------
#define A_Y      0        // float[256*36] 36864 : staging / features (union: phase-E scratch, head weights+small)
#define A_E      36864    // uint2[4096] 32768 : dst-sorted edges  (head: S30@+0 12000B, inv int[256]@+12032)
#define A_ROWS   69632    // int[257] 1056
#define A_NS     70688    // float[256]
#define A_ND     71712    // float[256]
#define A_BS     72736    // float[97] -> 512
#define A_KEYS   73248    // float[256]
#define A_Y4     74272    // float[256] (later: col-96 values)
#define A_SEL    75296    // int[32] -> 128
#define A_ORD    75424    // ushort[256] 512
#define A_RNS    75936    // float[256] 1024 : sqrt(clamped out-degree), to reconstruct h3 from Y
#define A_TOTAL  76960

// phase-E scratch inside Y region
#define E_EWRAW  0        // float[4096] 16384
#define E_RAWSD  16384    // uint[4096] 16384
#define E_DEGI   32768    // int[256]
#define E_DEGO   33792    // int[256]
#define E_CUR    34816    // int[256]  (end 35840 <= 36864)

// head scratch inside Y region (used only after feature dump)
#define H_C1W    0        // float[1552] 6208
#define H_C2W    6208     // float[2560] 10240
#define H_L1     16448    // float[480] 1920
#define H_Q      18368    // float[240] 960
#define H_RR     19328    // float[352] 1408
#define H_FF     20736    // float[128] 512   (end 21248 <= 36864)

// aggregate one node's edges over 32-dim Y rows (stride 36); lane handles 4 dims (quad q).
// unroll-2, sequential f64 accumulation (order-robust), returns tanh-activated h quad.
__device__ __forceinline__ float4 agg_node(const uint2* sE, int rs, int re,
                                           const float* Y, int q, float ndn,
                                           const float* Bs, int boff)
{
    double a0 = 0.0, a1 = 0.0, a2 = 0.0, a3 = 0.0;
    int e = rs;
    for (; e + 2 <= re; e += 2) {
        const uint2 ea = sE[e], eb = sE[e + 1];
        const float4 ya = *(const float4*)(Y + ea.y * 36 + q * 4);
        const float4 yb = *(const float4*)(Y + eb.y * 36 + q * 4);
        const double wa = (double)__uint_as_float(ea.x);
        const double wb = (double)__uint_as_float(eb.x);
        a0 += (double)ya.x * wa; a1 += (double)ya.y * wa;
        a2 += (double)ya.z * wa; a3 += (double)ya.w * wa;
        a0 += (double)yb.x * wb; a1 += (double)yb.y * wb;
        a2 += (double)yb.z * wb; a3 += (double)yb.w * wb;
    }
    if (e < re) {
        const uint2 ea = sE[e];
        const float4 ya = *(const float4*)(Y + ea.y * 36 + q * 4);
        const double wa = (double)__uint_as_float(ea.x);
        a0 += (double)ya.x * wa; a1 += (double)ya.y * wa;
        a2 += (double)ya.z * wa; a3 += (double)ya.w * wa;
    }
    const double sc = (double)ndn;
    float4 hv;
    hv.x = tanhf((float)(a0 * sc) + Bs[boff + q * 4 + 0]);
    hv.y = tanhf((float)(a1 * sc) + Bs[boff + q * 4 + 1]);
    hv.z = tanhf((float)(a2 * sc) + Bs[boff + q * 4 + 2]);
    hv.w = tanhf((float)(a3 * sc) + Bs[boff + q * 4 + 3]);
    return hv;
}

// in-place matvec on Y: row n <- (row n) @ W (wave-lockstep read-before-write)
__device__ __forceinline__ void matvec_inplace(float* Y, const float* __restrict__ W,
                                               int j, int nb)
{
    float wc[32];
    #pragma unroll
    for (int d = 0; d < 32; ++d) wc[d] = W[d * 32 + j];
    float acc[8];
    #pragma unroll
    for (int i2 = 0; i2 < 8; ++i2) {
        const float4* ar = (const float4*)(Y + (nb * 8 + i2) * 36);
        float a = 0.f;
        #pragma unroll
        for (int d8 = 0; d8 < 8; ++d8) {
            const float4 av = ar[d8];
            a = fmaf(av.x, wc[4 * d8 + 0], a);
            a = fmaf(av.y, wc[4 * d8 + 1], a);
            a = fmaf(av.z, wc[4 * d8 + 2], a);
            a = fmaf(av.w, wc[4 * d8 + 3], a);
        }
        acc[i2] = a;
    }
    #pragma unroll
    for (int i2 = 0; i2 < 8; ++i2) Y[(nb * 8 + i2) * 36 + j] = acc[i2];
}

// R10: no min-waves clause — let the allocator pick (~100 VGPR), 1 block/CU, ZERO spill.
// (1024,8)->32 VGPR and (1024,4)->64 VGPR both spilled 0.8-2.2 GB of scratch (R8/R9).
extern "C" __global__ void __launch_bounds__(1024)
dgcnn_fused(const int* __restrict__ feats, const int* __restrict__ node_id,
            const int* __restrict__ edge_id, const int* __restrict__ src,
            const int* __restrict__ dst,
            const float* __restrict__ ndata, const float* __restrict__ edata,
            const float* __restrict__ node_emb,
            const float* __restrict__ W0, const float* __restrict__ b0,
            const float* __restrict__ W1, const float* __restrict__ b1,
            const float* __restrict__ W2, const float* __restrict__ b2,
            const float* __restrict__ W3, const float* __restrict__ b3,
            const float* __restrict__ c1w, const float* __restrict__ c1b,
            const float* __restrict__ c2w, const float* __restrict__ c2b,
            const float* __restrict__ f1w, const float* __restrict__ f1b,
            const float* __restrict__ f2w, const float* __restrict__ f2b,
            float* __restrict__ out)
{
    extern __shared__ char smem[];
    float*  Y    = (float*)(smem + A_Y);
    uint2*  sE   = (uint2*)(smem + A_E);
    int*    rowS = (int*)(smem + A_ROWS);
    float*  ns   = (float*)(smem + A_NS);
    float*  nd   = (float*)(smem + A_ND);
    float*  Bs   = (float*)(smem + A_BS);
    float*  keys = (float*)(smem + A_KEYS);
    float*  y4   = (float*)(smem + A_Y4);
    int*    selI = (int*)(smem + A_SEL);
    ushort* ord  = (ushort*)(smem + A_ORD);
    float*  rnsb = (float*)(smem + A_RNS);

    const int g = blockIdx.x, t = threadIdx.x;
    const int lane = t & 63, wv = t >> 6;

    // ---------------- phase E: degrees, counting-sort edges by dst, degree-sort nodes ----------------
    {
        float* ewRaw = (float*)((char*)Y + E_EWRAW);
        uint*  rawSD = (uint*)((char*)Y + E_RAWSD);
        int*   degI  = (int*)((char*)Y + E_DEGI);
        int*   degO  = (int*)((char*)Y + E_DEGO);
        int*   cur   = (int*)((char*)Y + E_CUR);

        if (t < NPG) { degI[t] = 0; degO[t] = 0; keys[t] = -INFINITY; }
        if (t < 97) Bs[t] = (t < 32) ? b0[t] : (t < 64) ? b1[t - 32]
                           : (t < 96) ? b2[t - 64] : b3[0];
        __syncthreads();
        for (int e = t; e < EPG; e += 1024) {
            const int ge = g * EPG + e;
            const int s = src[ge] - g * NPG;
            const int d = dst[ge] - g * NPG;
            rawSD[e] = (uint)s | ((uint)d << 16);
            ewRaw[e] = edata[edge_id[ge]];
            atomicAdd(&degO[s], 1);
            atomicAdd(&degI[d], 1);
        }
        __syncthreads();
        if (t < 64) {   // single-wave shuffle prefix scan of degI -> rowS
            const int d0 = degI[4 * t], d1 = degI[4 * t + 1],
                      d2 = degI[4 * t + 2], d3 = degI[4 * t + 3];
            const int p1 = d0, p2 = p1 + d1, p3 = p2 + d2, p4 = p3 + d3;
            int s = p4;
            #pragma unroll
            for (int off = 1; off <= 32; off <<= 1) {
                const int o = __shfl_up(s, off, 64);
                if (lane >= off) s += o;
            }
            const int excl = s - p4;
            rowS[4 * t + 1] = excl + p1;
            rowS[4 * t + 2] = excl + p2;
            rowS[4 * t + 3] = excl + p3;
            rowS[4 * t + 4] = excl + p4;
            if (t == 0) rowS[0] = 0;
        }
        __syncthreads();
        if (t < NPG) {
            const int dOc = degO[t] > 0 ? degO[t] : 1;
            ns[t]   = (float)(1.0 / sqrt((double)dOc));
            rnsb[t] = sqrtf((float)dOc);
            nd[t]   = (float)(1.0 / sqrt((double)(degI[t] > 0 ? degI[t] : 1)));
            cur[t]  = rowS[t];
        }
        __syncthreads();
        for (int e = t; e < EPG; e += 1024) {
            const uint sd = rawSD[e];
            const int d = (int)(sd >> 16), s = (int)(sd & 0xffffu);
            const int pos = atomicAdd(&cur[d], 1);
            sE[pos] = make_uint2(__float_as_uint(ewRaw[e]), (uint)s);
        }
        __syncthreads();
        // degree-sort nodes (counting sort by clamped in-degree) -> ord
        if (t < NPG) degO[t] = 0;
        __syncthreads();
        if (t < NPG) atomicAdd(&degO[min(degI[t], 255)], 1);
        __syncthreads();
        if (t < 64) {
            const int d0 = degO[4 * t], d1 = degO[4 * t + 1],
                      d2 = degO[4 * t + 2], d3 = degO[4 * t + 3];
            const int p1 = d0, p2 = p1 + d1, p3 = p2 + d2, p4 = p3 + d3;
            int s = p4;
            #pragma unroll
            for (int off = 1; off <= 32; off <<= 1) {
                const int o = __shfl_up(s, off, 64);
                if (lane >= off) s += o;
            }
            const int excl = s - p4;
            cur[4 * t]     = excl;
            cur[4 * t + 1] = excl + p1;
            cur[4 * t + 2] = excl + p2;
            cur[4 * t + 3] = excl + p3;
        }
        __syncthreads();
        if (t < NPG) {
            const int pos = atomicAdd(&cur[min(degI[t], 255)], 1);
            ord[pos] = (ushort)t;
        }
        __syncthreads();
    }

    const int j = t & 31, nb = t >> 5;
    const int q = t & 7, g3 = (t >> 3) & 7;
    // balanced chunk pairing: wave wv aggregates sorted-degree chunks {wv, 31-wv}
    const int n0 = ord[wv * 8 + g3];
    const int n1 = ord[(31 - wv) * 8 + g3];
    const int rs0 = rowS[n0], re0 = rowS[n0 + 1];
    const int rs1 = rowS[n1], re1 = rowS[n1 + 1];
    const float nd0 = nd[n0], nd1 = nd[n1];
    const float ns0 = ns[n0], ns1 = ns[n1];

    // ---------------- Layer 1: y1 = (x*ns) @ W0 via 4 input chunks, reg-prefetched ----------------
    {
        const int na_ = t >> 3;                 // node for slot (t)
        const int nb2 = na_ + 128;              // node for slot (t+1024)
        const int gna = g * NPG + na_, gnb = g * NPG + nb2;
        const int nidA = node_id[gna], fidA = feats[gna];
        const int nidB = node_id[gnb], fidB = feats[gnb];
        const float sa = ns[na_], sb = ns[nb2];

        float4 xa, xb;
        xa = *(const float4*)(ndata + (size_t)nidA * 64 + q * 4);
        xb = *(const float4*)(ndata + (size_t)nidB * 64 + q * 4);
        float acc[8] = {0.f, 0.f, 0.f, 0.f, 0.f, 0.f, 0.f, 0.f};
        #pragma unroll
        for (int c = 0; c < 4; ++c) {
            float4 oa; oa.x = xa.x * sa; oa.y = xa.y * sa; oa.z = xa.z * sa; oa.w = xa.w * sa;
            float4 ob; ob.x = xb.x * sb; ob.y = xb.y * sb; ob.z = xb.z * sb; ob.w = xb.w * sb;
            *(float4*)(Y + na_ * 36 + q * 4) = oa;
            *(float4*)(Y + nb2 * 36 + q * 4) = ob;
            if (c < 3) {   // prefetch next chunk under barrier+matvec
                const int j0 = (c + 1) * 32 + q * 4;
                if (j0 < 64) {
                    xa = *(const float4*)(ndata + (size_t)nidA * 64 + j0);
                    xb = *(const float4*)(ndata + (size_t)nidB * 64 + j0);
                } else if (j0 < 96) {
                    xa = *(const float4*)(node_emb + (size_t)fidA * 32 + (j0 - 64));
                    xb = *(const float4*)(node_emb + (size_t)fidB * 32 + (j0 - 64));
                } else {
                    xa = *(const float4*)(node_emb + (size_t)(NATTR + nidA) * 32 + (j0 - 96));
                    xb = *(const float4*)(node_emb + (size_t)(NATTR + nidB) * 32 + (j0 - 96));
                }
            }
            __syncthreads();
            float wc[32];
            #pragma unroll
            for (int d = 0; d < 32; ++d) wc[d] = W0[(c * 32 + d) * 32 + j];
            #pragma unroll
            for (int i2 = 0; i2 < 8; ++i2) {
                const float4* ar = (const float4*)(Y + (nb * 8 + i2) * 36);
                float a = acc[i2];
                #pragma unroll
                for (int d8 = 0; d8 < 8; ++d8) {
                    const float4 av = ar[d8];
                    a = fmaf(av.x, wc[4 * d8 + 0], a);
                    a = fmaf(av.y, wc[4 * d8 + 1], a);
                    a = fmaf(av.z, wc[4 * d8 + 2], a);
                    a = fmaf(av.w, wc[4 * d8 + 3], a);
                }
                acc[i2] = a;
            }
            __syncthreads();
        }
        #pragma unroll
        for (int i2 = 0; i2 < 8; ++i2) Y[(nb * 8 + i2) * 36 + j] = acc[i2];
        __syncthreads();
    }

    // ---------------- Layers 1..3: aggregate + in-place transform; h kept in registers ----------------
    float4 hA0, hA1, hB0, hB1;      // layer-1/2 h quads for nodes n0 (A) and n1 (B)
    #define LAYER_STEP(BOFF, WNEXT, SAVE0, SAVE1, DO_SAVE, DO_MATVEC)                  \
    {                                                                                  \
        const float4 h0 = agg_node(sE, rs0, re0, Y, q, nd0, Bs, BOFF);                 \
        const float4 h1 = agg_node(sE, rs1, re1, Y, q, nd1, Bs, BOFF);                 \
        if (DO_SAVE) { SAVE0 = h0; SAVE1 = h1; }                                       \
        float m0 = fmaxf(fmaxf(h0.x, h0.y), fmaxf(h0.z, h0.w));                        \
        float m1 = fmaxf(fmaxf(h1.x, h1.y), fmaxf(h1.z, h1.w));                        \
        m0 = fmaxf(m0, __shfl_xor(m0, 1, 64));                                         \
        m0 = fmaxf(m0, __shfl_xor(m0, 2, 64));                                         \
        m0 = fmaxf(m0, __shfl_xor(m0, 4, 64));                                         \
        m1 = fmaxf(m1, __shfl_xor(m1, 1, 64));                                         \
        m1 = fmaxf(m1, __shfl_xor(m1, 2, 64));                                         \
        m1 = fmaxf(m1, __shfl_xor(m1, 4, 64));                                         \
        if (q == 0) {                                                                  \
            keys[n0] = fmaxf(keys[n0], m0);                                            \
            keys[n1] = fmaxf(keys[n1], m1);                                            \
        }                                                                              \
        __syncthreads();                       /* all agg reads of Y done */           \
        float4 w0v; w0v.x = h0.x * ns0; w0v.y = h0.y * ns0;                            \
                    w0v.z = h0.z * ns0; w0v.w = h0.w * ns0;                            \
        float4 w1v; w1v.x = h1.x * ns1; w1v.y = h1.y * ns1;                            \
                    w1v.z = h1.z * ns1; w1v.w = h1.w * ns1;                            \
        *(float4*)(Y + n0 * 36 + q * 4) = w0v;                                         \
        *(float4*)(Y + n1 * 36 + q * 4) = w1v;                                         \
        __syncthreads();                       /* h*ns rows complete */                \
        if (DO_MATVEC) {                                                               \
            matvec_inplace(Y, WNEXT, j, nb);                                           \
            __syncthreads();                                                           \
        }                                                                              \
    }
    LAYER_STEP(0,  W1, hA0, hB0, true,  true)
    LAYER_STEP(32, W2, hA1, hB1, true,  true)
    LAYER_STEP(64, W2, hA1, hB1, false, false)   // layer 3: no save (recon from Y), no matvec
    #undef LAYER_STEP

    // ---------------- Layer 4: y4 = (h3*ns) @ W3, scalar aggregate -> col 96 ----------------
    if (t < NPG) {
        const float4* fr = (const float4*)(Y + t * 36);
        float a = 0.f;
        #pragma unroll
        for (int d8 = 0; d8 < 8; ++d8) {
            const float4 h = fr[d8];
            a = fmaf(h.x, W3[4 * d8 + 0], a);
            a = fmaf(h.y, W3[4 * d8 + 1], a);
            a = fmaf(h.z, W3[4 * d8 + 2], a);
            a = fmaf(h.w, W3[4 * d8 + 3], a);
        }
        y4[t] = a;
    }
    __syncthreads();
    {
        const int n4 = ord[t >> 2], p = t & 3;
        const int rs = rowS[n4], re = rowS[n4 + 1];
        double a = 0.0;
        for (int e = rs + p; e < re; e += 4) {
            const uint2 ed = sE[e];
            a += (double)__uint_as_float(ed.x) * (double)y4[ed.y];
        }
        a += __shfl_xor(a, 1, 64);
        a += __shfl_xor(a, 2, 64);
        __syncthreads();                        // all y4 reads done before overwrite
        if (p == 0) {
            const float h = tanhf((float)(a * (double)nd[n4]) + Bs[96]);
            y4[n4] = h;                         // y4 now holds col-96 values
            keys[n4] = fmaxf(keys[n4], h);
        }
    }
    __syncthreads();

    // ---------------- head: top-30 -> dump selected rows -> sort -> CNN ----------------
    float* S30  = (float*)(smem + A_E);                 // sE dead
    int*   inv  = (int*)(smem + A_E + 12032);
    float* c1wS = (float*)(smem + A_Y + H_C1W);
    float* c2wS = (float*)(smem + A_Y + H_C2W);
    float* L1   = (float*)(smem + A_Y + H_L1);
    float* Q    = (float*)(smem + A_Y + H_Q);
    float* Rr   = (float*)(smem + A_Y + H_RR);
    float* Ff   = (float*)(smem + A_Y + H_FF);

    if (t < 64) {
        // wave 0: top-30, jax.lax.top_k tie semantics (desc value, asc index)
        // NOTE: no runtime indexing into kv/ki (rule #20: would go to scratch)
        float kv0 = keys[lane * 4 + 0], kv1 = keys[lane * 4 + 1];
        float kv2 = keys[lane * 4 + 2], kv3 = keys[lane * 4 + 3];
        for (int it = 0; it < 30; ++it) {
            float bv = kv0; int bi = lane * 4;
            if (kv1 > bv) { bv = kv1; bi = lane * 4 + 1; }
            if (kv2 > bv) { bv = kv2; bi = lane * 4 + 2; }
            if (kv3 > bv) { bv = kv3; bi = lane * 4 + 3; }
            #pragma unroll
            for (int off = 1; off <= 32; off <<= 1) {
                const float ov = __shfl_xor(bv, off, 64);
                const int   oi = __shfl_xor(bi, off, 64);
                if (ov > bv || (ov == bv && oi < bi)) { bv = ov; bi = oi; }
            }
            if (lane == 0) selI[it] = bi;
            if ((bi >> 2) == lane) {
                const int r = bi & 3;
                if (r == 0)      kv0 = -INFINITY;
                else if (r == 1) kv1 = -INFINITY;
                else if (r == 2) kv2 = -INFINITY;
                else             kv3 = -INFINITY;
            }
        }
    }
    if (t < NPG) inv[t] = -1;
    __syncthreads();
    if (t < 30) inv[selI[t]] = t;
    __syncthreads();

    // dump selected rows: cols 0..31 (hA0/hB0), 32..63 (hA1/hB1), 64..95 (Y*rns), 96 (y4)
    {
        const int s0 = inv[n0];
        if (s0 >= 0) {
            *(float4*)(S30 + s0 * 100 +      q * 4) = hA0;
            *(float4*)(S30 + s0 * 100 + 32 + q * 4) = hA1;
            const float4 y3 = *(const float4*)(Y + n0 * 36 + q * 4);
            const float r0 = rnsb[n0];
            float4 h3; h3.x = y3.x * r0; h3.y = y3.y * r0; h3.z = y3.z * r0; h3.w = y3.w * r0;
            *(float4*)(S30 + s0 * 100 + 64 + q * 4) = h3;
        }
        const int s1 = inv[n1];
        if (s1 >= 0) {
            *(float4*)(S30 + s1 * 100 +      q * 4) = hB0;
            *(float4*)(S30 + s1 * 100 + 32 + q * 4) = hB1;
            const float4 y3 = *(const float4*)(Y + n1 * 36 + q * 4);
            const float r1 = rnsb[n1];
            float4 h3; h3.x = y3.x * r1; h3.y = y3.y * r1; h3.z = y3.z * r1; h3.w = y3.w * r1;
            *(float4*)(S30 + s1 * 100 + 64 + q * 4) = h3;
        }
        if (t < 30) S30[t * 100 + 96] = y4[selI[t]];
    }
    __syncthreads();

    // Y region now free: load conv weights; sort the 30 rows (bitonic-128, ascending)
    for (int i = t; i < 1552; i += 1024) c1wS[i] = c1w[i];
    for (int i = t; i < 2560; i += 1024) c2wS[i] = c2w[i];
    for (int k = wv; k < 30; k += 16) {
        float v0 = S30[k * 100 + lane];
        float v1 = (lane < 33) ? S30[k * 100 + 64 + lane] : INFINITY;
        for (int kk = 2; kk <= 128; kk <<= 1) {
            for (int jj = kk >> 1; jj > 0; jj >>= 1) {
                if (jj == 64) {
                    const float lo = fminf(v0, v1), hi = fmaxf(v0, v1);
                    v0 = lo; v1 = hi;
                } else {
                    const float p0 = __shfl_xor(v0, jj, 64);
                    const float p1 = __shfl_xor(v1, jj, 64);
                    const bool up   = ((lane & jj) == 0);
                    const bool asc0 = (kk == 128) ? true : ((lane & kk) == 0);
                    const bool asc1 = (kk == 128) ? true : (((64 + lane) & kk) == 0);
                    v0 = (up == asc0) ? fminf(v0, p0) : fmaxf(v0, p0);
                    v1 = (up == asc1) ? fminf(v1, p1) : fmaxf(v1, p1);
                }
            }
        }
        S30[k * 100 + lane] = v0;
        if (lane < 33) S30[k * 100 + 64 + lane] = v1;
    }
    __syncthreads();

    // conv1 (16 ch, kernel 97, stride 97) + relu
    if (t < 480) {
        const int k = t >> 4, c = t & 15;
        const float* row  = S30 + k * 100;
        const float* wrow = c1wS + c * 97;
        float acc = c1b[c];
        for (int d = 0; d < 97; ++d) acc = fmaf(row[d], wrow[d], acc);
        L1[k * 16 + c] = fmaxf(acc, 0.f);
    }
    __syncthreads();
    if (t < 240) {
        const int c = t / 15, tt = t % 15;
        Q[c * 15 + tt] = fmaxf(L1[(2 * tt) * 16 + c], L1[(2 * tt + 1) * 16 + c]);
    }
    __syncthreads();
    if (t < 352) {
        const int o = t / 11, tt = t % 11;
        const float* wo = c2wS + o * 80;
        float acc = c2b[o];
        #pragma unroll
        for (int c = 0; c < 16; ++c)
            #pragma unroll
            for (int jj = 0; jj < 5; ++jj)
                acc = fmaf(Q[c * 15 + tt + jj], wo[c * 5 + jj], acc);
        Rr[o * 11 + tt] = fmaxf(acc, 0.f);
    }
    __syncthreads();
    if (t < 128) {
        float acc = f1b[t];
        const float* wr = f1w + t * 352;
        for (int i = 0; i < 352; ++i) acc = fmaf(Rr[i], wr[i], acc);
        Ff[t] = fmaxf(acc, 0.f);
    }
    __syncthreads();
    if (t < 64) {
        float acc = Ff[lane] * f2w[lane] + Ff[lane + 64] * f2w[lane + 64];
        #pragma unroll
        for (int off = 1; off <= 32; off <<= 1) acc += __shfl_xor(acc, off, 64);
        if (lane == 0) out[g] = acc + f2b[0];
    }
}

extern "C" void kernel_launch(void* const* d_in, const int* in_sizes, int n_in,
                              void* d_out, int out_size, void* d_ws, size_t ws_size,
                              hipStream_t stream)
{
    const int*   feats    = (const int*)d_in[0];
    const int*   node_id  = (const int*)d_in[1];
    const int*   edge_id  = (const int*)d_in[2];
    const int*   src      = (const int*)d_in[3];
    const int*   dst      = (const int*)d_in[4];
    const float* ndata    = (const float*)d_in[5];
    const float* edata    = (const float*)d_in[6];
    const float* node_emb = (const float*)d_in[7];
    const float* W0 = (const float*)d_in[8];
    const float* b0 = (const float*)d_in[9];
    const float* W1 = (const float*)d_in[10];
    const float* b1 = (const float*)d_in[11];
    const float* W2 = (const float*)d_in[12];
    const float* b2 = (const float*)d_in[13];
    const float* W3 = (const float*)d_in[14];
    const float* b3 = (const float*)d_in[15];
    const float* c1w = (const float*)d_in[16];
    const float* c1b = (const float*)d_in[17];
    const float* c2w = (const float*)d_in[18];
    const float* c2b = (const float*)d_in[19];
    const float* f1w = (const float*)d_in[20];
    const float* f1b = (const float*)d_in[21];
    const float* f2w = (const float*)d_in[22];
    const float* f2b = (const float*)d_in[23];

    (void)hipFuncSetAttribute((const void*)dgcnn_fused,
                              hipFuncAttributeMaxDynamicSharedMemorySize, A_TOTAL);

    dgcnn_fused<<<NGRAPH, 1024, A_TOTAL, stream>>>(feats, node_id, edge_id, src, dst,
                                                   ndata, edata, node_emb,
                                                   W0, b0, W1, b1, W2, b2, W3, b3,
                                                   c1w, c1b, c2w, c2b,
                                                   f1w, f1b, f2w, f2b,
                                                   (float*)d_out);
}

// Round 11
// 661.123 us; speedup vs baseline: 1.0034x; 1.0034x over previous
//
#include <hip/hip_runtime.h>
#include <math.h>

#define NPG    256
#define EPG    4096
#define NGRAPH 1024
#define NATTR  100000

// ---------------- LDS layout (bytes), total 76,960 ----------------
#define A_Y      0        // float[256*36] 36864 : staging / features (union: phase-E scratch, head weights+small)
#define A_E      36864    // uint2[4096] 32768 : dst-sorted edges  (head: S30@+0 12000B, inv int[256]@+12032)
#define A_ROWS   69632    // int[257] 1056
#define A_NS     70688    // float[256]
#define A_ND     71712    // float[256]
#define A_BS     72736    // float[97] -> 512
#define A_KEYS   73248    // float[256]
#define A_Y4     74272    // float[256] (later: col-96 values)
#define A_SEL    75296    // int[32] -> 128
#define A_ORD    75424    // ushort[256] 512
#define A_RNS    75936    // float[256] 1024 : sqrt(clamped out-degree), to reconstruct h3 from Y
#define A_TOTAL  76960

// phase-E scratch inside Y region
#define E_EWRAW  0        // float[4096] 16384
#define E_RAWSD  16384    // uint[4096] 16384
#define E_DEGI   32768    // int[256]
#define E_DEGO   33792    // int[256]
#define E_CUR    34816    // int[256]  (end 35840 <= 36864)

// head scratch inside Y region (used only after feature dump)
#define H_C1W    0        // float[1552] 6208
#define H_C2W    6208     // float[2560] 10240
#define H_L1     16448    // float[480] 1920
#define H_Q      18368    // float[240] 960
#define H_RR     19328    // float[352] 1408
#define H_FF     20736    // float[128] 512   (end 21248 <= 36864)

// aggregate one node's edges over 32-dim Y rows (stride 36); lane handles 4 dims (quad q).
// unroll-2, sequential f64 accumulation (order-robust), returns tanh-activated h quad.
__device__ __forceinline__ float4 agg_node(const uint2* sE, int rs, int re,
                                           const float* Y, int q, float ndn,
                                           const float* Bs, int boff)
{
    double a0 = 0.0, a1 = 0.0, a2 = 0.0, a3 = 0.0;
    int e = rs;
    for (; e + 2 <= re; e += 2) {
        const uint2 ea = sE[e], eb = sE[e + 1];
        const float4 ya = *(const float4*)(Y + ea.y * 36 + q * 4);
        const float4 yb = *(const float4*)(Y + eb.y * 36 + q * 4);
        const double wa = (double)__uint_as_float(ea.x);
        const double wb = (double)__uint_as_float(eb.x);
        a0 += (double)ya.x * wa; a1 += (double)ya.y * wa;
        a2 += (double)ya.z * wa; a3 += (double)ya.w * wa;
        a0 += (double)yb.x * wb; a1 += (double)yb.y * wb;
        a2 += (double)yb.z * wb; a3 += (double)yb.w * wb;
    }
    if (e < re) {
        const uint2 ea = sE[e];
        const float4 ya = *(const float4*)(Y + ea.y * 36 + q * 4);
        const double wa = (double)__uint_as_float(ea.x);
        a0 += (double)ya.x * wa; a1 += (double)ya.y * wa;
        a2 += (double)ya.z * wa; a3 += (double)ya.w * wa;
    }
    const double sc = (double)ndn;
    float4 hv;
    hv.x = tanhf((float)(a0 * sc) + Bs[boff + q * 4 + 0]);
    hv.y = tanhf((float)(a1 * sc) + Bs[boff + q * 4 + 1]);
    hv.z = tanhf((float)(a2 * sc) + Bs[boff + q * 4 + 2]);
    hv.w = tanhf((float)(a3 * sc) + Bs[boff + q * 4 + 3]);
    return hv;
}

// in-place matvec on Y: row n <- (row n) @ W (wave-lockstep read-before-write)
__device__ __forceinline__ void matvec_inplace(float* Y, const float* __restrict__ W,
                                               int j, int nb)
{
    float wc[32];
    #pragma unroll
    for (int d = 0; d < 32; ++d) wc[d] = W[d * 32 + j];
    float acc[8];
    #pragma unroll
    for (int i2 = 0; i2 < 8; ++i2) {
        const float4* ar = (const float4*)(Y + (nb * 8 + i2) * 36);
        float a = 0.f;
        #pragma unroll
        for (int d8 = 0; d8 < 8; ++d8) {
            const float4 av = ar[d8];
            a = fmaf(av.x, wc[4 * d8 + 0], a);
            a = fmaf(av.y, wc[4 * d8 + 1], a);
            a = fmaf(av.z, wc[4 * d8 + 2], a);
            a = fmaf(av.w, wc[4 * d8 + 3], a);
        }
        acc[i2] = a;
    }
    #pragma unroll
    for (int i2 = 0; i2 < 8; ++i2) Y[(nb * 8 + i2) * 36 + j] = acc[i2];
}

// R11: (1024,1) — min-waves/EU=1 lifts the VGPR target to the workgroup-feasible max
// (flat-wg-size 1024 forces 4 waves/SIMD -> backend cap 128). Empirical map so far:
// (1024,8)->32 VGPR, (1024,4)->64, (1024)->64 — all spill 0.8-2.2 GB (R8-R10).
extern "C" __global__ void __launch_bounds__(1024, 1)
dgcnn_fused(const int* __restrict__ feats, const int* __restrict__ node_id,
            const int* __restrict__ edge_id, const int* __restrict__ src,
            const int* __restrict__ dst,
            const float* __restrict__ ndata, const float* __restrict__ edata,
            const float* __restrict__ node_emb,
            const float* __restrict__ W0, const float* __restrict__ b0,
            const float* __restrict__ W1, const float* __restrict__ b1,
            const float* __restrict__ W2, const float* __restrict__ b2,
            const float* __restrict__ W3, const float* __restrict__ b3,
            const float* __restrict__ c1w, const float* __restrict__ c1b,
            const float* __restrict__ c2w, const float* __restrict__ c2b,
            const float* __restrict__ f1w, const float* __restrict__ f1b,
            const float* __restrict__ f2w, const float* __restrict__ f2b,
            float* __restrict__ out)
{
    extern __shared__ char smem[];
    float*  Y    = (float*)(smem + A_Y);
    uint2*  sE   = (uint2*)(smem + A_E);
    int*    rowS = (int*)(smem + A_ROWS);
    float*  ns   = (float*)(smem + A_NS);
    float*  nd   = (float*)(smem + A_ND);
    float*  Bs   = (float*)(smem + A_BS);
    float*  keys = (float*)(smem + A_KEYS);
    float*  y4   = (float*)(smem + A_Y4);
    int*    selI = (int*)(smem + A_SEL);
    ushort* ord  = (ushort*)(smem + A_ORD);
    float*  rnsb = (float*)(smem + A_RNS);

    const int g = blockIdx.x, t = threadIdx.x;
    const int lane = t & 63, wv = t >> 6;

    // ---------------- phase E: degrees, counting-sort edges by dst, degree-sort nodes ----------------
    {
        float* ewRaw = (float*)((char*)Y + E_EWRAW);
        uint*  rawSD = (uint*)((char*)Y + E_RAWSD);
        int*   degI  = (int*)((char*)Y + E_DEGI);
        int*   degO  = (int*)((char*)Y + E_DEGO);
        int*   cur   = (int*)((char*)Y + E_CUR);

        if (t < NPG) { degI[t] = 0; degO[t] = 0; keys[t] = -INFINITY; }
        if (t < 97) Bs[t] = (t < 32) ? b0[t] : (t < 64) ? b1[t - 32]
                           : (t < 96) ? b2[t - 64] : b3[0];
        __syncthreads();
        for (int e = t; e < EPG; e += 1024) {
            const int ge = g * EPG + e;
            const int s = src[ge] - g * NPG;
            const int d = dst[ge] - g * NPG;
            rawSD[e] = (uint)s | ((uint)d << 16);
            ewRaw[e] = edata[edge_id[ge]];
            atomicAdd(&degO[s], 1);
            atomicAdd(&degI[d], 1);
        }
        __syncthreads();
        if (t < 64) {   // single-wave shuffle prefix scan of degI -> rowS
            const int d0 = degI[4 * t], d1 = degI[4 * t + 1],
                      d2 = degI[4 * t + 2], d3 = degI[4 * t + 3];
            const int p1 = d0, p2 = p1 + d1, p3 = p2 + d2, p4 = p3 + d3;
            int s = p4;
            #pragma unroll
            for (int off = 1; off <= 32; off <<= 1) {
                const int o = __shfl_up(s, off, 64);
                if (lane >= off) s += o;
            }
            const int excl = s - p4;
            rowS[4 * t + 1] = excl + p1;
            rowS[4 * t + 2] = excl + p2;
            rowS[4 * t + 3] = excl + p3;
            rowS[4 * t + 4] = excl + p4;
            if (t == 0) rowS[0] = 0;
        }
        __syncthreads();
        if (t < NPG) {
            const int dOc = degO[t] > 0 ? degO[t] : 1;
            ns[t]   = (float)(1.0 / sqrt((double)dOc));
            rnsb[t] = sqrtf((float)dOc);
            nd[t]   = (float)(1.0 / sqrt((double)(degI[t] > 0 ? degI[t] : 1)));
            cur[t]  = rowS[t];
        }
        __syncthreads();
        for (int e = t; e < EPG; e += 1024) {
            const uint sd = rawSD[e];
            const int d = (int)(sd >> 16), s = (int)(sd & 0xffffu);
            const int pos = atomicAdd(&cur[d], 1);
            sE[pos] = make_uint2(__float_as_uint(ewRaw[e]), (uint)s);
        }
        __syncthreads();
        // degree-sort nodes (counting sort by clamped in-degree) -> ord
        if (t < NPG) degO[t] = 0;
        __syncthreads();
        if (t < NPG) atomicAdd(&degO[min(degI[t], 255)], 1);
        __syncthreads();
        if (t < 64) {
            const int d0 = degO[4 * t], d1 = degO[4 * t + 1],
                      d2 = degO[4 * t + 2], d3 = degO[4 * t + 3];
            const int p1 = d0, p2 = p1 + d1, p3 = p2 + d2, p4 = p3 + d3;
            int s = p4;
            #pragma unroll
            for (int off = 1; off <= 32; off <<= 1) {
                const int o = __shfl_up(s, off, 64);
                if (lane >= off) s += o;
            }
            const int excl = s - p4;
            cur[4 * t]     = excl;
            cur[4 * t + 1] = excl + p1;
            cur[4 * t + 2] = excl + p2;
            cur[4 * t + 3] = excl + p3;
        }
        __syncthreads();
        if (t < NPG) {
            const int pos = atomicAdd(&cur[min(degI[t], 255)], 1);
            ord[pos] = (ushort)t;
        }
        __syncthreads();
    }

    const int j = t & 31, nb = t >> 5;
    const int q = t & 7, g3 = (t >> 3) & 7;
    // balanced chunk pairing: wave wv aggregates sorted-degree chunks {wv, 31-wv}
    const int n0 = ord[wv * 8 + g3];
    const int n1 = ord[(31 - wv) * 8 + g3];
    const int rs0 = rowS[n0], re0 = rowS[n0 + 1];
    const int rs1 = rowS[n1], re1 = rowS[n1 + 1];
    const float nd0 = nd[n0], nd1 = nd[n1];
    const float ns0 = ns[n0], ns1 = ns[n1];

    // ---------------- Layer 1: y1 = (x*ns) @ W0 via 4 input chunks, reg-prefetched ----------------
    {
        const int na_ = t >> 3;                 // node for slot (t)
        const int nb2 = na_ + 128;              // node for slot (t+1024)
        const int gna = g * NPG + na_, gnb = g * NPG + nb2;
        const int nidA = node_id[gna], fidA = feats[gna];
        const int nidB = node_id[gnb], fidB = feats[gnb];
        const float sa = ns[na_], sb = ns[nb2];

        float4 xa, xb;
        xa = *(const float4*)(ndata + (size_t)nidA * 64 + q * 4);
        xb = *(const float4*)(ndata + (size_t)nidB * 64 + q * 4);
        float acc[8] = {0.f, 0.f, 0.f, 0.f, 0.f, 0.f, 0.f, 0.f};
        #pragma unroll
        for (int c = 0; c < 4; ++c) {
            float4 oa; oa.x = xa.x * sa; oa.y = xa.y * sa; oa.z = xa.z * sa; oa.w = xa.w * sa;
            float4 ob; ob.x = xb.x * sb; ob.y = xb.y * sb; ob.z = xb.z * sb; ob.w = xb.w * sb;
            *(float4*)(Y + na_ * 36 + q * 4) = oa;
            *(float4*)(Y + nb2 * 36 + q * 4) = ob;
            if (c < 3) {   // prefetch next chunk under barrier+matvec
                const int j0 = (c + 1) * 32 + q * 4;
                if (j0 < 64) {
                    xa = *(const float4*)(ndata + (size_t)nidA * 64 + j0);
                    xb = *(const float4*)(ndata + (size_t)nidB * 64 + j0);
                } else if (j0 < 96) {
                    xa = *(const float4*)(node_emb + (size_t)fidA * 32 + (j0 - 64));
                    xb = *(const float4*)(node_emb + (size_t)fidB * 32 + (j0 - 64));
                } else {
                    xa = *(const float4*)(node_emb + (size_t)(NATTR + nidA) * 32 + (j0 - 96));
                    xb = *(const float4*)(node_emb + (size_t)(NATTR + nidB) * 32 + (j0 - 96));
                }
            }
            __syncthreads();
            float wc[32];
            #pragma unroll
            for (int d = 0; d < 32; ++d) wc[d] = W0[(c * 32 + d) * 32 + j];
            #pragma unroll
            for (int i2 = 0; i2 < 8; ++i2) {
                const float4* ar = (const float4*)(Y + (nb * 8 + i2) * 36);
                float a = acc[i2];
                #pragma unroll
                for (int d8 = 0; d8 < 8; ++d8) {
                    const float4 av = ar[d8];
                    a = fmaf(av.x, wc[4 * d8 + 0], a);
                    a = fmaf(av.y, wc[4 * d8 + 1], a);
                    a = fmaf(av.z, wc[4 * d8 + 2], a);
                    a = fmaf(av.w, wc[4 * d8 + 3], a);
                }
                acc[i2] = a;
            }
            __syncthreads();
        }
        #pragma unroll
        for (int i2 = 0; i2 < 8; ++i2) Y[(nb * 8 + i2) * 36 + j] = acc[i2];
        __syncthreads();
    }

    // ---------------- Layers 1..3: aggregate + in-place transform; h kept in registers ----------------
    float4 hA0, hA1, hB0, hB1;      // layer-1/2 h quads for nodes n0 (A) and n1 (B)
    #define LAYER_STEP(BOFF, WNEXT, SAVE0, SAVE1, DO_SAVE, DO_MATVEC)                  \
    {                                                                                  \
        const float4 h0 = agg_node(sE, rs0, re0, Y, q, nd0, Bs, BOFF);                 \
        const float4 h1 = agg_node(sE, rs1, re1, Y, q, nd1, Bs, BOFF);                 \
        if (DO_SAVE) { SAVE0 = h0; SAVE1 = h1; }                                       \
        float m0 = fmaxf(fmaxf(h0.x, h0.y), fmaxf(h0.z, h0.w));                        \
        float m1 = fmaxf(fmaxf(h1.x, h1.y), fmaxf(h1.z, h1.w));                        \
        m0 = fmaxf(m0, __shfl_xor(m0, 1, 64));                                         \
        m0 = fmaxf(m0, __shfl_xor(m0, 2, 64));                                         \
        m0 = fmaxf(m0, __shfl_xor(m0, 4, 64));                                         \
        m1 = fmaxf(m1, __shfl_xor(m1, 1, 64));                                         \
        m1 = fmaxf(m1, __shfl_xor(m1, 2, 64));                                         \
        m1 = fmaxf(m1, __shfl_xor(m1, 4, 64));                                         \
        if (q == 0) {                                                                  \
            keys[n0] = fmaxf(keys[n0], m0);                                            \
            keys[n1] = fmaxf(keys[n1], m1);                                            \
        }                                                                              \
        __syncthreads();                       /* all agg reads of Y done */           \
        float4 w0v; w0v.x = h0.x * ns0; w0v.y = h0.y * ns0;                            \
                    w0v.z = h0.z * ns0; w0v.w = h0.w * ns0;                            \
        float4 w1v; w1v.x = h1.x * ns1; w1v.y = h1.y * ns1;                            \
                    w1v.z = h1.z * ns1; w1v.w = h1.w * ns1;                            \
        *(float4*)(Y + n0 * 36 + q * 4) = w0v;                                         \
        *(float4*)(Y + n1 * 36 + q * 4) = w1v;                                         \
        __syncthreads();                       /* h*ns rows complete */                \
        if (DO_MATVEC) {                                                               \
            matvec_inplace(Y, WNEXT, j, nb);                                           \
            __syncthreads();                                                           \
        }                                                                              \
    }
    LAYER_STEP(0,  W1, hA0, hB0, true,  true)
    LAYER_STEP(32, W2, hA1, hB1, true,  true)
    LAYER_STEP(64, W2, hA1, hB1, false, false)   // layer 3: no save (recon from Y), no matvec
    #undef LAYER_STEP

    // ---------------- Layer 4: y4 = (h3*ns) @ W3, scalar aggregate -> col 96 ----------------
    if (t < NPG) {
        const float4* fr = (const float4*)(Y + t * 36);
        float a = 0.f;
        #pragma unroll
        for (int d8 = 0; d8 < 8; ++d8) {
            const float4 h = fr[d8];
            a = fmaf(h.x, W3[4 * d8 + 0], a);
            a = fmaf(h.y, W3[4 * d8 + 1], a);
            a = fmaf(h.z, W3[4 * d8 + 2], a);
            a = fmaf(h.w, W3[4 * d8 + 3], a);
        }
        y4[t] = a;
    }
    __syncthreads();
    {
        const int n4 = ord[t >> 2], p = t & 3;
        const int rs = rowS[n4], re = rowS[n4 + 1];
        double a = 0.0;
        for (int e = rs + p; e < re; e += 4) {
            const uint2 ed = sE[e];
            a += (double)__uint_as_float(ed.x) * (double)y4[ed.y];
        }
        a += __shfl_xor(a, 1, 64);
        a += __shfl_xor(a, 2, 64);
        __syncthreads();                        // all y4 reads done before overwrite
        if (p == 0) {
            const float h = tanhf((float)(a * (double)nd[n4]) + Bs[96]);
            y4[n4] = h;                         // y4 now holds col-96 values
            keys[n4] = fmaxf(keys[n4], h);
        }
    }
    __syncthreads();

    // ---------------- head: top-30 -> dump selected rows -> sort -> CNN ----------------
    float* S30  = (float*)(smem + A_E);                 // sE dead
    int*   inv  = (int*)(smem + A_E + 12032);
    float* c1wS = (float*)(smem + A_Y + H_C1W);
    float* c2wS = (float*)(smem + A_Y + H_C2W);
    float* L1   = (float*)(smem + A_Y + H_L1);
    float* Q    = (float*)(smem + A_Y + H_Q);
    float* Rr   = (float*)(smem + A_Y + H_RR);
    float* Ff   = (float*)(smem + A_Y + H_FF);

    if (t < 64) {
        // wave 0: top-30, jax.lax.top_k tie semantics (desc value, asc index)
        // NOTE: no runtime indexing into kv/ki (rule #20: would go to scratch)
        float kv0 = keys[lane * 4 + 0], kv1 = keys[lane * 4 + 1];
        float kv2 = keys[lane * 4 + 2], kv3 = keys[lane * 4 + 3];
        for (int it = 0; it < 30; ++it) {
            float bv = kv0; int bi = lane * 4;
            if (kv1 > bv) { bv = kv1; bi = lane * 4 + 1; }
            if (kv2 > bv) { bv = kv2; bi = lane * 4 + 2; }
            if (kv3 > bv) { bv = kv3; bi = lane * 4 + 3; }
            #pragma unroll
            for (int off = 1; off <= 32; off <<= 1) {
                const float ov = __shfl_xor(bv, off, 64);
                const int   oi = __shfl_xor(bi, off, 64);
                if (ov > bv || (ov == bv && oi < bi)) { bv = ov; bi = oi; }
            }
            if (lane == 0) selI[it] = bi;
            if ((bi >> 2) == lane) {
                const int r = bi & 3;
                if (r == 0)      kv0 = -INFINITY;
                else if (r == 1) kv1 = -INFINITY;
                else if (r == 2) kv2 = -INFINITY;
                else             kv3 = -INFINITY;
            }
        }
    }
    if (t < NPG) inv[t] = -1;
    __syncthreads();
    if (t < 30) inv[selI[t]] = t;
    __syncthreads();

    // dump selected rows: cols 0..31 (hA0/hB0), 32..63 (hA1/hB1), 64..95 (Y*rns), 96 (y4)
    {
        const int s0 = inv[n0];
        if (s0 >= 0) {
            *(float4*)(S30 + s0 * 100 +      q * 4) = hA0;
            *(float4*)(S30 + s0 * 100 + 32 + q * 4) = hA1;
            const float4 y3 = *(const float4*)(Y + n0 * 36 + q * 4);
            const float r0 = rnsb[n0];
            float4 h3; h3.x = y3.x * r0; h3.y = y3.y * r0; h3.z = y3.z * r0; h3.w = y3.w * r0;
            *(float4*)(S30 + s0 * 100 + 64 + q * 4) = h3;
        }
        const int s1 = inv[n1];
        if (s1 >= 0) {
            *(float4*)(S30 + s1 * 100 +      q * 4) = hB0;
            *(float4*)(S30 + s1 * 100 + 32 + q * 4) = hB1;
            const float4 y3 = *(const float4*)(Y + n1 * 36 + q * 4);
            const float r1 = rnsb[n1];
            float4 h3; h3.x = y3.x * r1; h3.y = y3.y * r1; h3.z = y3.z * r1; h3.w = y3.w * r1;
            *(float4*)(S30 + s1 * 100 + 64 + q * 4) = h3;
        }
        if (t < 30) S30[t * 100 + 96] = y4[selI[t]];
    }
    __syncthreads();

    // Y region now free: load conv weights; sort the 30 rows (bitonic-128, ascending)
    for (int i = t; i < 1552; i += 1024) c1wS[i] = c1w[i];
    for (int i = t; i < 2560; i += 1024) c2wS[i] = c2w[i];
    for (int k = wv; k < 30; k += 16) {
        float v0 = S30[k * 100 + lane];
        float v1 = (lane < 33) ? S30[k * 100 + 64 + lane] : INFINITY;
        for (int kk = 2; kk <= 128; kk <<= 1) {
            for (int jj = kk >> 1; jj > 0; jj >>= 1) {
                if (jj == 64) {
                    const float lo = fminf(v0, v1), hi = fmaxf(v0, v1);
                    v0 = lo; v1 = hi;
                } else {
                    const float p0 = __shfl_xor(v0, jj, 64);
                    const float p1 = __shfl_xor(v1, jj, 64);
                    const bool up   = ((lane & jj) == 0);
                    const bool asc0 = (kk == 128) ? true : ((lane & kk) == 0);
                    const bool asc1 = (kk == 128) ? true : (((64 + lane) & kk) == 0);
                    v0 = (up == asc0) ? fminf(v0, p0) : fmaxf(v0, p0);
                    v1 = (up == asc1) ? fminf(v1, p1) : fmaxf(v1, p1);
                }
            }
        }
        S30[k * 100 + lane] = v0;
        if (lane < 33) S30[k * 100 + 64 + lane] = v1;
    }
    __syncthreads();

    // conv1 (16 ch, kernel 97, stride 97) + relu
    if (t < 480) {
        const int k = t >> 4, c = t & 15;
        const float* row  = S30 + k * 100;
        const float* wrow = c1wS + c * 97;
        float acc = c1b[c];
        for (int d = 0; d < 97; ++d) acc = fmaf(row[d], wrow[d], acc);
        L1[k * 16 + c] = fmaxf(acc, 0.f);
    }
    __syncthreads();
    if (t < 240) {
        const int c = t / 15, tt = t % 15;
        Q[c * 15 + tt] = fmaxf(L1[(2 * tt) * 16 + c], L1[(2 * tt + 1) * 16 + c]);
    }
    __syncthreads();
    if (t < 352) {
        const int o = t / 11, tt = t % 11;
        const float* wo = c2wS + o * 80;
        float acc = c2b[o];
        #pragma unroll
        for (int c = 0; c < 16; ++c)
            #pragma unroll
            for (int jj = 0; jj < 5; ++jj)
                acc = fmaf(Q[c * 15 + tt + jj], wo[c * 5 + jj], acc);
        Rr[o * 11 + tt] = fmaxf(acc, 0.f);
    }
    __syncthreads();
    if (t < 128) {
        float acc = f1b[t];
        const float* wr = f1w + t * 352;
        for (int i = 0; i < 352; ++i) acc = fmaf(Rr[i], wr[i], acc);
        Ff[t] = fmaxf(acc, 0.f);
    }
    __syncthreads();
    if (t < 64) {
        float acc = Ff[lane] * f2w[lane] + Ff[lane + 64] * f2w[lane + 64];
        #pragma unroll
        for (int off = 1; off <= 32; off <<= 1) acc += __shfl_xor(acc, off, 64);
        if (lane == 0) out[g] = acc + f2b[0];
    }
}

extern "C" void kernel_launch(void* const* d_in, const int* in_sizes, int n_in,
                              void* d_out, int out_size, void* d_ws, size_t ws_size,
                              hipStream_t stream)
{
    const int*   feats    = (const int*)d_in[0];
    const int*   node_id  = (const int*)d_in[1];
    const int*   edge_id  = (const int*)d_in[2];
    const int*   src      = (const int*)d_in[3];
    const int*   dst      = (const int*)d_in[4];
    const float* ndata    = (const float*)d_in[5];
    const float* edata    = (const float*)d_in[6];
    const float* node_emb = (const float*)d_in[7];
    const float* W0 = (const float*)d_in[8];
    const float* b0 = (const float*)d_in[9];
    const float* W1 = (const float*)d_in[10];
    const float* b1 = (const float*)d_in[11];
    const float* W2 = (const float*)d_in[12];
    const float* b2 = (const float*)d_in[13];
    const float* W3 = (const float*)d_in[14];
    const float* b3 = (const float*)d_in[15];
    const float* c1w = (const float*)d_in[16];
    const float* c1b = (const float*)d_in[17];
    const float* c2w = (const float*)d_in[18];
    const float* c2b = (const float*)d_in[19];
    const float* f1w = (const float*)d_in[20];
    const float* f1b = (const float*)d_in[21];
    const float* f2w = (const float*)d_in[22];
    const float* f2b = (const float*)d_in[23];

    (void)hipFuncSetAttribute((const void*)dgcnn_fused,
                              hipFuncAttributeMaxDynamicSharedMemorySize, A_TOTAL);

    dgcnn_fused<<<NGRAPH, 1024, A_TOTAL, stream>>>(feats, node_id, edge_id, src, dst,
                                                   ndata, edata, node_emb,
                                                   W0, b0, W1, b1, W2, b2, W3, b3,
                                                   c1w, c1b, c2w, c2b,
                                                   f1w, f1b, f2w, f2b,
                                                   (float*)d_out);
}

// Round 12
// 651.878 us; speedup vs baseline: 1.0176x; 1.0142x over previous
//
#include <hip/hip_runtime.h>
#include <math.h>

#define NPG    256
#define EPG    4096
#define NGRAPH 1024
#define NATTR  100000

// ---------------- LDS layout (bytes), total 161,760 <= 163,840 (1 block/CU; regs are the binding limit) ----------------
#define A_F     0         // float[256][100] 102400 : full feature rows.
                          //  cols 0..31 h1 | 32..63 h2 | 64..95 Y-staging then h3 | 96 h4 | 97 y4 scratch
#define A_E     102400    // uint2[4104] 32832 : dst-sorted edges {w_bits, src} (+pad)
#define A_ROWS  135232    // int[257] 1056
#define A_NS    136288    // float[256]
#define A_ND    137312    // float[256]
#define A_BS    138336    // float[97] -> 512
#define A_KEYS  138848    // float[256]
#define A_SEL   139872    // int[32] -> 128
#define A_ORD   140000    // ushort[256] 512
#define A_C1W   140512    // float[1552] 6208
#define A_C2W   146720    // float[2560] 10240
#define A_HL1   156960    // float[480] 1920
#define A_HQ    158880    // float[240] 960
#define A_HRR   159840    // float[352] 1408
#define A_HFF   161248    // float[128] 512
#define A_TOTAL 161760

// phase-E scratch inside F region (dead before layer 1)
#define E_EWRAW 0         // float[4096] 16384
#define E_RAWSD 16384     // uint[4096] 16384
#define E_DEGI  32768     // int[256]
#define E_DEGO  33792     // int[256]
#define E_CUR   34816     // int[256]  (end 35840 << 102400)

// aggregate one node's edges over Y = F cols 64..95 (row stride 100); lane owns quad q.
// unroll-2, sequential f64 accumulation (order-robust); returns tanh-activated h quad.
__device__ __forceinline__ float4 agg_node(const uint2* sE, int rs, int re,
                                           const float* F, int q, float ndn,
                                           const float* Bs, int boff)
{
    double a0 = 0.0, a1 = 0.0, a2 = 0.0, a3 = 0.0;
    int e = rs;
    for (; e + 2 <= re; e += 2) {
        const uint2 ea = sE[e], eb = sE[e + 1];
        const float4 ya = *(const float4*)(F + ea.y * 100 + 64 + q * 4);
        const float4 yb = *(const float4*)(F + eb.y * 100 + 64 + q * 4);
        const double wa = (double)__uint_as_float(ea.x);
        const double wb = (double)__uint_as_float(eb.x);
        a0 += (double)ya.x * wa; a1 += (double)ya.y * wa;
        a2 += (double)ya.z * wa; a3 += (double)ya.w * wa;
        a0 += (double)yb.x * wb; a1 += (double)yb.y * wb;
        a2 += (double)yb.z * wb; a3 += (double)yb.w * wb;
    }
    if (e < re) {
        const uint2 ea = sE[e];
        const float4 ya = *(const float4*)(F + ea.y * 100 + 64 + q * 4);
        const double wa = (double)__uint_as_float(ea.x);
        a0 += (double)ya.x * wa; a1 += (double)ya.y * wa;
        a2 += (double)ya.z * wa; a3 += (double)ya.w * wa;
    }
    const double sc = (double)ndn;
    float4 hv;
    hv.x = tanhf((float)(a0 * sc) + Bs[boff + q * 4 + 0]);
    hv.y = tanhf((float)(a1 * sc) + Bs[boff + q * 4 + 1]);
    hv.z = tanhf((float)(a2 * sc) + Bs[boff + q * 4 + 2]);
    hv.w = tanhf((float)(a3 * sc) + Bs[boff + q * 4 + 3]);
    return hv;
}

// in-place matvec on Y (F cols 64..95): row n <- (row n) @ W (wave-lockstep read-before-write)
__device__ __forceinline__ void matvec_inplace(float* F, const float* __restrict__ W,
                                               int j, int nb)
{
    float wc[32];
    #pragma unroll
    for (int d = 0; d < 32; ++d) wc[d] = W[d * 32 + j];
    float acc[8];
    #pragma unroll
    for (int i2 = 0; i2 < 8; ++i2) {
        const float4* ar = (const float4*)(F + (nb * 8 + i2) * 100 + 64);
        float a = 0.f;
        #pragma unroll
        for (int d8 = 0; d8 < 8; ++d8) {
            const float4 av = ar[d8];
            a = fmaf(av.x, wc[4 * d8 + 0], a);
            a = fmaf(av.y, wc[4 * d8 + 1], a);
            a = fmaf(av.z, wc[4 * d8 + 2], a);
            a = fmaf(av.w, wc[4 * d8 + 3], a);
        }
        acc[i2] = a;
    }
    #pragma unroll
    for (int i2 = 0; i2 < 8; ++i2) F[(nb * 8 + i2) * 100 + 64 + j] = acc[i2];
}

extern "C" __global__ void __launch_bounds__(1024, 1)
dgcnn_fused(const int* __restrict__ feats, const int* __restrict__ node_id,
            const int* __restrict__ edge_id, const int* __restrict__ src,
            const int* __restrict__ dst,
            const float* __restrict__ ndata, const float* __restrict__ edata,
            const float* __restrict__ node_emb,
            const float* __restrict__ W0, const float* __restrict__ b0,
            const float* __restrict__ W1, const float* __restrict__ b1,
            const float* __restrict__ W2, const float* __restrict__ b2,
            const float* __restrict__ W3, const float* __restrict__ b3,
            const float* __restrict__ c1w, const float* __restrict__ c1b,
            const float* __restrict__ c2w, const float* __restrict__ c2b,
            const float* __restrict__ f1w, const float* __restrict__ f1b,
            const float* __restrict__ f2w, const float* __restrict__ f2b,
            float* __restrict__ out)
{
    extern __shared__ char smem[];
    float*  F    = (float*)(smem + A_F);
    uint2*  sE   = (uint2*)(smem + A_E);
    int*    rowS = (int*)(smem + A_ROWS);
    float*  ns   = (float*)(smem + A_NS);
    float*  nd   = (float*)(smem + A_ND);
    float*  Bs   = (float*)(smem + A_BS);
    float*  keys = (float*)(smem + A_KEYS);
    int*    selI = (int*)(smem + A_SEL);
    ushort* ord  = (ushort*)(smem + A_ORD);
    float*  c1wS = (float*)(smem + A_C1W);
    float*  c2wS = (float*)(smem + A_C2W);
    float*  L1   = (float*)(smem + A_HL1);
    float*  Q    = (float*)(smem + A_HQ);
    float*  Rr   = (float*)(smem + A_HRR);
    float*  Ff   = (float*)(smem + A_HFF);

    const int g = blockIdx.x, t = threadIdx.x;
    const int lane = t & 63, wv = t >> 6;

    // ---------------- phase E: degrees, counting-sort edges by dst, degree-sort nodes ----------------
    {
        float* ewRaw = (float*)((char*)F + E_EWRAW);
        uint*  rawSD = (uint*)((char*)F + E_RAWSD);
        int*   degI  = (int*)((char*)F + E_DEGI);
        int*   degO  = (int*)((char*)F + E_DEGO);
        int*   cur   = (int*)((char*)F + E_CUR);

        if (t < NPG) { degI[t] = 0; degO[t] = 0; keys[t] = -INFINITY; }
        if (t < 97) Bs[t] = (t < 32) ? b0[t] : (t < 64) ? b1[t - 32]
                           : (t < 96) ? b2[t - 64] : b3[0];
        __syncthreads();
        for (int e = t; e < EPG; e += 1024) {
            const int ge = g * EPG + e;
            const int s = src[ge] - g * NPG;
            const int d = dst[ge] - g * NPG;
            rawSD[e] = (uint)s | ((uint)d << 16);
            ewRaw[e] = edata[edge_id[ge]];
            atomicAdd(&degO[s], 1);
            atomicAdd(&degI[d], 1);
        }
        __syncthreads();
        if (t < 64) {   // single-wave shuffle prefix scan of degI -> rowS
            const int d0 = degI[4 * t], d1 = degI[4 * t + 1],
                      d2 = degI[4 * t + 2], d3 = degI[4 * t + 3];
            const int p1 = d0, p2 = p1 + d1, p3 = p2 + d2, p4 = p3 + d3;
            int s = p4;
            #pragma unroll
            for (int off = 1; off <= 32; off <<= 1) {
                const int o = __shfl_up(s, off, 64);
                if (lane >= off) s += o;
            }
            const int excl = s - p4;
            rowS[4 * t + 1] = excl + p1;
            rowS[4 * t + 2] = excl + p2;
            rowS[4 * t + 3] = excl + p3;
            rowS[4 * t + 4] = excl + p4;
            if (t == 0) rowS[0] = 0;
        }
        __syncthreads();
        if (t < NPG) {
            ns[t] = (float)(1.0 / sqrt((double)(degO[t] > 0 ? degO[t] : 1)));
            nd[t] = (float)(1.0 / sqrt((double)(degI[t] > 0 ? degI[t] : 1)));
            cur[t] = rowS[t];
        }
        if (t < 8) sE[4096 + t] = make_uint2(0u, 0u);   // pad
        __syncthreads();
        for (int e = t; e < EPG; e += 1024) {
            const uint sd = rawSD[e];
            const int d = (int)(sd >> 16), s = (int)(sd & 0xffffu);
            const int pos = atomicAdd(&cur[d], 1);
            sE[pos] = make_uint2(__float_as_uint(ewRaw[e]), (uint)s);
        }
        __syncthreads();
        // degree-sort nodes (counting sort by clamped in-degree) -> ord
        if (t < NPG) degO[t] = 0;
        __syncthreads();
        if (t < NPG) atomicAdd(&degO[min(degI[t], 255)], 1);
        __syncthreads();
        if (t < 64) {
            const int d0 = degO[4 * t], d1 = degO[4 * t + 1],
                      d2 = degO[4 * t + 2], d3 = degO[4 * t + 3];
            const int p1 = d0, p2 = p1 + d1, p3 = p2 + d2, p4 = p3 + d3;
            int s = p4;
            #pragma unroll
            for (int off = 1; off <= 32; off <<= 1) {
                const int o = __shfl_up(s, off, 64);
                if (lane >= off) s += o;
            }
            const int excl = s - p4;
            cur[4 * t]     = excl;
            cur[4 * t + 1] = excl + p1;
            cur[4 * t + 2] = excl + p2;
            cur[4 * t + 3] = excl + p3;
        }
        __syncthreads();
        if (t < NPG) {
            const int pos = atomicAdd(&cur[min(degI[t], 255)], 1);
            ord[pos] = (ushort)t;
        }
        __syncthreads();
    }

    const int j = t & 31, nb = t >> 5;
    const int q = t & 7, g3 = (t >> 3) & 7;
    // balanced chunk pairing: wave wv aggregates sorted-degree chunks {wv, 31-wv}
    const int n0 = ord[wv * 8 + g3];
    const int n1 = ord[(31 - wv) * 8 + g3];
    const int rs0 = rowS[n0], re0 = rowS[n0 + 1];
    const int rs1 = rowS[n1], re1 = rowS[n1 + 1];
    const float nd0 = nd[n0], nd1 = nd[n1];
    const float ns0 = ns[n0], ns1 = ns[n1];

    // ---------------- Layer 1: y1 = (x*ns) @ W0 via 4 input chunks (staged in F cols 64..95) ----------------
    {
        const int na_ = t >> 3;                 // node for slot (t)
        const int nb2 = na_ + 128;              // node for slot (t+1024)
        const int gna = g * NPG + na_, gnb = g * NPG + nb2;
        const int nidA = node_id[gna], fidA = feats[gna];
        const int nidB = node_id[gnb], fidB = feats[gnb];
        const float sa = ns[na_], sb = ns[nb2];

        float4 xa, xb;
        xa = *(const float4*)(ndata + (size_t)nidA * 64 + q * 4);
        xb = *(const float4*)(ndata + (size_t)nidB * 64 + q * 4);
        float acc[8] = {0.f, 0.f, 0.f, 0.f, 0.f, 0.f, 0.f, 0.f};
        #pragma unroll
        for (int c = 0; c < 4; ++c) {
            float4 oa; oa.x = xa.x * sa; oa.y = xa.y * sa; oa.z = xa.z * sa; oa.w = xa.w * sa;
            float4 ob; ob.x = xb.x * sb; ob.y = xb.y * sb; ob.z = xb.z * sb; ob.w = xb.w * sb;
            *(float4*)(F + na_ * 100 + 64 + q * 4) = oa;
            *(float4*)(F + nb2 * 100 + 64 + q * 4) = ob;
            if (c < 3) {   // prefetch next chunk under barrier+matvec
                const int j0 = (c + 1) * 32 + q * 4;
                if (j0 < 64) {
                    xa = *(const float4*)(ndata + (size_t)nidA * 64 + j0);
                    xb = *(const float4*)(ndata + (size_t)nidB * 64 + j0);
                } else if (j0 < 96) {
                    xa = *(const float4*)(node_emb + (size_t)fidA * 32 + (j0 - 64));
                    xb = *(const float4*)(node_emb + (size_t)fidB * 32 + (j0 - 64));
                } else {
                    xa = *(const float4*)(node_emb + (size_t)(NATTR + nidA) * 32 + (j0 - 96));
                    xb = *(const float4*)(node_emb + (size_t)(NATTR + nidB) * 32 + (j0 - 96));
                }
            }
            __syncthreads();
            float wc[32];
            #pragma unroll
            for (int d = 0; d < 32; ++d) wc[d] = W0[(c * 32 + d) * 32 + j];
            #pragma unroll
            for (int i2 = 0; i2 < 8; ++i2) {
                const float4* ar = (const float4*)(F + (nb * 8 + i2) * 100 + 64);
                float a = acc[i2];
                #pragma unroll
                for (int d8 = 0; d8 < 8; ++d8) {
                    const float4 av = ar[d8];
                    a = fmaf(av.x, wc[4 * d8 + 0], a);
                    a = fmaf(av.y, wc[4 * d8 + 1], a);
                    a = fmaf(av.z, wc[4 * d8 + 2], a);
                    a = fmaf(av.w, wc[4 * d8 + 3], a);
                }
                acc[i2] = a;
            }
            __syncthreads();
        }
        #pragma unroll
        for (int i2 = 0; i2 < 8; ++i2) F[(nb * 8 + i2) * 100 + 64 + j] = acc[i2];
        __syncthreads();
    }

    // ---------------- Layers 1..3: aggregate (Y = F cols 64..95), h -> F cols, no register carry ----------------
    // H_TO_Y=false (L=0,1): h -> F cols BOFF (disjoint, pre-barrier); then Y <- h*ns; matvec WNEXT.
    // H_TO_Y=true  (L=2):   barrier; h -> F cols 64..95 in place (Y dead after).
    #define LAYER_STEP(BOFF, WNEXT, H_TO_Y)                                            \
    {                                                                                  \
        const float4 h0 = agg_node(sE, rs0, re0, F, q, nd0, Bs, BOFF);                 \
        const float4 h1 = agg_node(sE, rs1, re1, F, q, nd1, Bs, BOFF);                 \
        float m0 = fmaxf(fmaxf(h0.x, h0.y), fmaxf(h0.z, h0.w));                        \
        float m1 = fmaxf(fmaxf(h1.x, h1.y), fmaxf(h1.z, h1.w));                        \
        m0 = fmaxf(m0, __shfl_xor(m0, 1, 64));                                         \
        m0 = fmaxf(m0, __shfl_xor(m0, 2, 64));                                         \
        m0 = fmaxf(m0, __shfl_xor(m0, 4, 64));                                         \
        m1 = fmaxf(m1, __shfl_xor(m1, 1, 64));                                         \
        m1 = fmaxf(m1, __shfl_xor(m1, 2, 64));                                         \
        m1 = fmaxf(m1, __shfl_xor(m1, 4, 64));                                         \
        if (q == 0) {                                                                  \
            keys[n0] = fmaxf(keys[n0], m0);                                            \
            keys[n1] = fmaxf(keys[n1], m1);                                            \
        }                                                                              \
        if (!(H_TO_Y)) {                                                               \
            *(float4*)(F + n0 * 100 + (BOFF) + q * 4) = h0;   /* disjoint from Y */    \
            *(float4*)(F + n1 * 100 + (BOFF) + q * 4) = h1;                            \
            __syncthreads();                   /* all agg reads of Y done */           \
            float4 w0v; w0v.x = h0.x * ns0; w0v.y = h0.y * ns0;                        \
                        w0v.z = h0.z * ns0; w0v.w = h0.w * ns0;                        \
            float4 w1v; w1v.x = h1.x * ns1; w1v.y = h1.y * ns1;                        \
                        w1v.z = h1.z * ns1; w1v.w = h1.w * ns1;                        \
            *(float4*)(F + n0 * 100 + 64 + q * 4) = w0v;                               \
            *(float4*)(F + n1 * 100 + 64 + q * 4) = w1v;                               \
            __syncthreads();                   /* h*ns rows complete */                \
            matvec_inplace(F, WNEXT, j, nb);                                           \
            __syncthreads();                                                           \
        } else {                                                                       \
            __syncthreads();                   /* all agg reads of Y done */           \
            *(float4*)(F + n0 * 100 + 64 + q * 4) = h0;   /* h3 in place */            \
            *(float4*)(F + n1 * 100 + 64 + q * 4) = h1;                                \
            __syncthreads();                                                           \
        }                                                                              \
    }
    LAYER_STEP(0,  W1, false)
    LAYER_STEP(32, W2, false)
    LAYER_STEP(64, W2, true)
    #undef LAYER_STEP

    // ---------------- Layer 4: y4 = ns * (h3 @ W3) -> col 97; scalar aggregate -> col 96 ----------------
    if (t < NPG) {
        const float4* fr = (const float4*)(F + t * 100 + 64);
        float a = 0.f;
        #pragma unroll
        for (int d8 = 0; d8 < 8; ++d8) {
            const float4 h = fr[d8];
            a = fmaf(h.x, W3[4 * d8 + 0], a);
            a = fmaf(h.y, W3[4 * d8 + 1], a);
            a = fmaf(h.z, W3[4 * d8 + 2], a);
            a = fmaf(h.w, W3[4 * d8 + 3], a);
        }
        F[t * 100 + 97] = a * ns[t];
    }
    __syncthreads();
    {
        const int n4 = ord[t >> 2], p = t & 3;
        const int rs = rowS[n4], re = rowS[n4 + 1];
        double a = 0.0;
        for (int e = rs + p; e < re; e += 4) {
            const uint2 ed = sE[e];
            a += (double)__uint_as_float(ed.x) * (double)F[ed.y * 100 + 97];
        }
        a += __shfl_xor(a, 1, 64);
        a += __shfl_xor(a, 2, 64);
        if (p == 0) {
            const float h = tanhf((float)(a * (double)nd[n4]) + Bs[96]);
            F[n4 * 100 + 96] = h;              // col 96 disjoint from col-97 reads
            keys[n4] = fmaxf(keys[n4], h);
        }
    }
    __syncthreads();

    // ---------------- head: top-30 -> in-place sort of selected rows -> CNN ----------------
    if (t < 64) {
        // wave 0: top-30, jax.lax.top_k tie semantics (desc value, asc index)
        float kv0 = keys[lane * 4 + 0], kv1 = keys[lane * 4 + 1];
        float kv2 = keys[lane * 4 + 2], kv3 = keys[lane * 4 + 3];
        for (int it = 0; it < 30; ++it) {
            float bv = kv0; int bi = lane * 4;
            if (kv1 > bv) { bv = kv1; bi = lane * 4 + 1; }
            if (kv2 > bv) { bv = kv2; bi = lane * 4 + 2; }
            if (kv3 > bv) { bv = kv3; bi = lane * 4 + 3; }
            #pragma unroll
            for (int off = 1; off <= 32; off <<= 1) {
                const float ov = __shfl_xor(bv, off, 64);
                const int   oi = __shfl_xor(bi, off, 64);
                if (ov > bv || (ov == bv && oi < bi)) { bv = ov; bi = oi; }
            }
            if (lane == 0) selI[it] = bi;
            if ((bi >> 2) == lane) {
                const int r = bi & 3;
                if (r == 0)      kv0 = -INFINITY;
                else if (r == 1) kv1 = -INFINITY;
                else if (r == 2) kv2 = -INFINITY;
                else             kv3 = -INFINITY;
            }
        }
    } else {
        for (int i = t - 64; i < 1552; i += 960) c1wS[i] = c1w[i];
        for (int i = t - 64; i < 2560; i += 960) c2wS[i] = c2w[i];
    }
    __syncthreads();

    // bitonic-128 sort (ascending) of the 30 selected rows, in place in F
    for (int k = wv; k < 30; k += 16) {
        float* fr = F + selI[k] * 100;
        float v0 = fr[lane];
        float v1 = (lane < 33) ? fr[64 + lane] : INFINITY;
        for (int kk = 2; kk <= 128; kk <<= 1) {
            for (int jj = kk >> 1; jj > 0; jj >>= 1) {
                if (jj == 64) {
                    const float lo = fminf(v0, v1), hi = fmaxf(v0, v1);
                    v0 = lo; v1 = hi;
                } else {
                    const float p0 = __shfl_xor(v0, jj, 64);
                    const float p1 = __shfl_xor(v1, jj, 64);
                    const bool up   = ((lane & jj) == 0);
                    const bool asc0 = (kk == 128) ? true : ((lane & kk) == 0);
                    const bool asc1 = (kk == 128) ? true : (((64 + lane) & kk) == 0);
                    v0 = (up == asc0) ? fminf(v0, p0) : fmaxf(v0, p0);
                    v1 = (up == asc1) ? fminf(v1, p1) : fmaxf(v1, p1);
                }
            }
        }
        fr[lane] = v0;
        if (lane < 33) fr[64 + lane] = v1;
    }
    __syncthreads();

    // conv1 (16 ch, kernel 97, stride 97) + relu
    if (t < 480) {
        const int k = t >> 4, c = t & 15;
        const float* row  = F + selI[k] * 100;
        const float* wrow = c1wS + c * 97;
        float acc = c1b[c];
        for (int d = 0; d < 97; ++d) acc = fmaf(row[d], wrow[d], acc);
        L1[k * 16 + c] = fmaxf(acc, 0.f);
    }
    __syncthreads();
    if (t < 240) {
        const int c = t / 15, tt = t % 15;
        Q[c * 15 + tt] = fmaxf(L1[(2 * tt) * 16 + c], L1[(2 * tt + 1) * 16 + c]);
    }
    __syncthreads();
    if (t < 352) {
        const int o = t / 11, tt = t % 11;
        const float* wo = c2wS + o * 80;
        float acc = c2b[o];
        #pragma unroll
        for (int c = 0; c < 16; ++c)
            #pragma unroll
            for (int jj = 0; jj < 5; ++jj)
                acc = fmaf(Q[c * 15 + tt + jj], wo[c * 5 + jj], acc);
        Rr[o * 11 + tt] = fmaxf(acc, 0.f);
    }
    __syncthreads();
    if (t < 128) {
        float acc = f1b[t];
        const float* wr = f1w + t * 352;
        for (int i = 0; i < 352; ++i) acc = fmaf(Rr[i], wr[i], acc);
        Ff[t] = fmaxf(acc, 0.f);
    }
    __syncthreads();
    if (t < 64) {
        float acc = Ff[lane] * f2w[lane] + Ff[lane + 64] * f2w[lane + 64];
        #pragma unroll
        for (int off = 1; off <= 32; off <<= 1) acc += __shfl_xor(acc, off, 64);
        if (lane == 0) out[g] = acc + f2b[0];
    }
}

extern "C" void kernel_launch(void* const* d_in, const int* in_sizes, int n_in,
                              void* d_out, int out_size, void* d_ws, size_t ws_size,
                              hipStream_t stream)
{
    const int*   feats    = (const int*)d_in[0];
    const int*   node_id  = (const int*)d_in[1];
    const int*   edge_id  = (const int*)d_in[2];
    const int*   src      = (const int*)d_in[3];
    const int*   dst      = (const int*)d_in[4];
    const float* ndata    = (const float*)d_in[5];
    const float* edata    = (const float*)d_in[6];
    const float* node_emb = (const float*)d_in[7];
    const float* W0 = (const float*)d_in[8];
    const float* b0 = (const float*)d_in[9];
    const float* W1 = (const float*)d_in[10];
    const float* b1 = (const float*)d_in[11];
    const float* W2 = (const float*)d_in[12];
    const float* b2 = (const float*)d_in[13];
    const float* W3 = (const float*)d_in[14];
    const float* b3 = (const float*)d_in[15];
    const float* c1w = (const float*)d_in[16];
    const float* c1b = (const float*)d_in[17];
    const float* c2w = (const float*)d_in[18];
    const float* c2b = (const float*)d_in[19];
    const float* f1w = (const float*)d_in[20];
    const float* f1b = (const float*)d_in[21];
    const float* f2w = (const float*)d_in[22];
    const float* f2b = (const float*)d_in[23];

    (void)hipFuncSetAttribute((const void*)dgcnn_fused,
                              hipFuncAttributeMaxDynamicSharedMemorySize, A_TOTAL);

    dgcnn_fused<<<NGRAPH, 1024, A_TOTAL, stream>>>(feats, node_id, edge_id, src, dst,
                                                   ndata, edata, node_emb,
                                                   W0, b0, W1, b1, W2, b2, W3, b3,
                                                   c1w, c1b, c2w, c2b,
                                                   f1w, f1b, f2w, f2b,
                                                   (float*)d_out);
}

// Round 13
// 400.448 us; speedup vs baseline: 1.6565x; 1.6279x over previous
//
#include <hip/hip_runtime.h>
#include <math.h>

#define NPG    256
#define EPG    4096
#define NGRAPH 1024
#define NATTR  100000

// ---------------- LDS layout (bytes), total 161,760 <= 163,840 (1 block/CU; VGPRs are the binding limit) ----------------
#define A_F     0         // float[256][100] 102400 : feature rows.
                          //  cols 0..31 x-stage then h1 | 32..63 h2 | 64..95 y/h3 | 96 h4 | 97 y4 scratch
#define A_E     102400    // uint2[4104] 32832 : dst-sorted edges {w_bits, src} (+pad)
#define A_ROWS  135232    // int[257] 1056
#define A_NS    136288    // float[256]
#define A_ND    137312    // float[256]
#define A_BS    138336    // float[97] -> 512
#define A_KEYS  138848    // float[256]
#define A_SEL   139872    // int[32] -> 128
#define A_ORD   140000    // ushort[256] 512
#define A_C1W   140512    // float[1552] 6208
#define A_C2W   146720    // float[2560] 10240
#define A_HL1   156960    // float[480] 1920
#define A_HQ    158880    // float[240] 960
#define A_HRR   159840    // float[352] 1408
#define A_HFF   161248    // float[128] 512
#define A_TOTAL 161760

// phase-E scratch inside F region (dead before layer 1)
#define E_EWRAW 0         // float[4096] 16384
#define E_RAWSD 16384     // uint[4096] 16384
#define E_DEGI  32768     // int[256]
#define E_DEGO  33792     // int[256]
#define E_CUR   34816     // int[256]  (end 35840 << 102400)

// aggregate one node's edges over Y = F cols 64..95 (row stride 100); lane owns quad q.
// unroll-2, sequential f64 accumulation (order-robust); returns tanh-activated h quad.
__device__ __forceinline__ float4 agg_node(const uint2* sE, int rs, int re,
                                           const float* F, int q, float ndn,
                                           const float* Bs, int boff)
{
    double a0 = 0.0, a1 = 0.0, a2 = 0.0, a3 = 0.0;
    int e = rs;
    for (; e + 2 <= re; e += 2) {
        const uint2 ea = sE[e], eb = sE[e + 1];
        const float4 ya = *(const float4*)(F + ea.y * 100 + 64 + q * 4);
        const float4 yb = *(const float4*)(F + eb.y * 100 + 64 + q * 4);
        const double wa = (double)__uint_as_float(ea.x);
        const double wb = (double)__uint_as_float(eb.x);
        a0 += (double)ya.x * wa; a1 += (double)ya.y * wa;
        a2 += (double)ya.z * wa; a3 += (double)ya.w * wa;
        a0 += (double)yb.x * wb; a1 += (double)yb.y * wb;
        a2 += (double)yb.z * wb; a3 += (double)yb.w * wb;
    }
    if (e < re) {
        const uint2 ea = sE[e];
        const float4 ya = *(const float4*)(F + ea.y * 100 + 64 + q * 4);
        const double wa = (double)__uint_as_float(ea.x);
        a0 += (double)ya.x * wa; a1 += (double)ya.y * wa;
        a2 += (double)ya.z * wa; a3 += (double)ya.w * wa;
    }
    const double sc = (double)ndn;
    float4 hv;
    hv.x = tanhf((float)(a0 * sc) + Bs[boff + q * 4 + 0]);
    hv.y = tanhf((float)(a1 * sc) + Bs[boff + q * 4 + 1]);
    hv.z = tanhf((float)(a2 * sc) + Bs[boff + q * 4 + 2]);
    hv.w = tanhf((float)(a3 * sc) + Bs[boff + q * 4 + 3]);
    return hv;
}

// in-place matvec on Y (F cols 64..95): row n <- (row n) @ W (wave-lockstep read-before-write:
// rows of group nb are read/written only by the 32 lockstep threads owning nb)
__device__ __forceinline__ void matvec_inplace(float* F, const float* __restrict__ W,
                                               int j, int nb)
{
    float wc[32];
    #pragma unroll
    for (int d = 0; d < 32; ++d) wc[d] = W[d * 32 + j];
    float acc[8];
    #pragma unroll
    for (int i2 = 0; i2 < 8; ++i2) {
        const float4* ar = (const float4*)(F + (nb * 8 + i2) * 100 + 64);
        float a = 0.f;
        #pragma unroll
        for (int d8 = 0; d8 < 8; ++d8) {
            const float4 av = ar[d8];
            a = fmaf(av.x, wc[4 * d8 + 0], a);
            a = fmaf(av.y, wc[4 * d8 + 1], a);
            a = fmaf(av.z, wc[4 * d8 + 2], a);
            a = fmaf(av.w, wc[4 * d8 + 3], a);
        }
        acc[i2] = a;
    }
    #pragma unroll
    for (int i2 = 0; i2 < 8; ++i2) F[(nb * 8 + i2) * 100 + 64 + j] = acc[i2];
}

extern "C" __global__ void __launch_bounds__(1024, 1)
dgcnn_fused(const int* __restrict__ feats, const int* __restrict__ node_id,
            const int* __restrict__ edge_id, const int* __restrict__ src,
            const int* __restrict__ dst,
            const float* __restrict__ ndata, const float* __restrict__ edata,
            const float* __restrict__ node_emb,
            const float* __restrict__ W0, const float* __restrict__ b0,
            const float* __restrict__ W1, const float* __restrict__ b1,
            const float* __restrict__ W2, const float* __restrict__ b2,
            const float* __restrict__ W3, const float* __restrict__ b3,
            const float* __restrict__ c1w, const float* __restrict__ c1b,
            const float* __restrict__ c2w, const float* __restrict__ c2b,
            const float* __restrict__ f1w, const float* __restrict__ f1b,
            const float* __restrict__ f2w, const float* __restrict__ f2b,
            float* __restrict__ out)
{
    extern __shared__ char smem[];
    float*  F    = (float*)(smem + A_F);
    uint2*  sE   = (uint2*)(smem + A_E);
    int*    rowS = (int*)(smem + A_ROWS);
    float*  ns   = (float*)(smem + A_NS);
    float*  nd   = (float*)(smem + A_ND);
    float*  Bs   = (float*)(smem + A_BS);
    float*  keys = (float*)(smem + A_KEYS);
    int*    selI = (int*)(smem + A_SEL);
    ushort* ord  = (ushort*)(smem + A_ORD);
    float*  c1wS = (float*)(smem + A_C1W);
    float*  c2wS = (float*)(smem + A_C2W);
    float*  L1   = (float*)(smem + A_HL1);
    float*  Q    = (float*)(smem + A_HQ);
    float*  Rr   = (float*)(smem + A_HRR);
    float*  Ff   = (float*)(smem + A_HFF);

    const int g = blockIdx.x, t = threadIdx.x;
    const int lane = t & 63, wv = t >> 6;

    // ---------------- phase E: degrees, counting-sort edges by dst, degree-sort nodes ----------------
    {
        float* ewRaw = (float*)((char*)F + E_EWRAW);
        uint*  rawSD = (uint*)((char*)F + E_RAWSD);
        int*   degI  = (int*)((char*)F + E_DEGI);
        int*   degO  = (int*)((char*)F + E_DEGO);
        int*   cur   = (int*)((char*)F + E_CUR);

        if (t < NPG) { degI[t] = 0; degO[t] = 0; keys[t] = -INFINITY; }
        if (t < 97) Bs[t] = (t < 32) ? b0[t] : (t < 64) ? b1[t - 32]
                           : (t < 96) ? b2[t - 64] : b3[0];
        __syncthreads();
        for (int e = t; e < EPG; e += 1024) {
            const int ge = g * EPG + e;
            const int s = src[ge] - g * NPG;
            const int d = dst[ge] - g * NPG;
            rawSD[e] = (uint)s | ((uint)d << 16);
            ewRaw[e] = edata[edge_id[ge]];
            atomicAdd(&degO[s], 1);
            atomicAdd(&degI[d], 1);
        }
        __syncthreads();
        if (t < 64) {   // single-wave shuffle prefix scan of degI -> rowS
            const int d0 = degI[4 * t], d1 = degI[4 * t + 1],
                      d2 = degI[4 * t + 2], d3 = degI[4 * t + 3];
            const int p1 = d0, p2 = p1 + d1, p3 = p2 + d2, p4 = p3 + d3;
            int s = p4;
            #pragma unroll
            for (int off = 1; off <= 32; off <<= 1) {
                const int o = __shfl_up(s, off, 64);
                if (lane >= off) s += o;
            }
            const int excl = s - p4;
            rowS[4 * t + 1] = excl + p1;
            rowS[4 * t + 2] = excl + p2;
            rowS[4 * t + 3] = excl + p3;
            rowS[4 * t + 4] = excl + p4;
            if (t == 0) rowS[0] = 0;
        }
        __syncthreads();
        if (t < NPG) {
            ns[t] = (float)(1.0 / sqrt((double)(degO[t] > 0 ? degO[t] : 1)));
            nd[t] = (float)(1.0 / sqrt((double)(degI[t] > 0 ? degI[t] : 1)));
            cur[t] = rowS[t];
        }
        if (t < 8) sE[4096 + t] = make_uint2(0u, 0u);   // pad
        __syncthreads();
        for (int e = t; e < EPG; e += 1024) {
            const uint sd = rawSD[e];
            const int d = (int)(sd >> 16), s = (int)(sd & 0xffffu);
            const int pos = atomicAdd(&cur[d], 1);
            sE[pos] = make_uint2(__float_as_uint(ewRaw[e]), (uint)s);
        }
        __syncthreads();
        // degree-sort nodes (counting sort by clamped in-degree) -> ord
        if (t < NPG) degO[t] = 0;
        __syncthreads();
        if (t < NPG) atomicAdd(&degO[min(degI[t], 255)], 1);
        __syncthreads();
        if (t < 64) {
            const int d0 = degO[4 * t], d1 = degO[4 * t + 1],
                      d2 = degO[4 * t + 2], d3 = degO[4 * t + 3];
            const int p1 = d0, p2 = p1 + d1, p3 = p2 + d2, p4 = p3 + d3;
            int s = p4;
            #pragma unroll
            for (int off = 1; off <= 32; off <<= 1) {
                const int o = __shfl_up(s, off, 64);
                if (lane >= off) s += o;
            }
            const int excl = s - p4;
            cur[4 * t]     = excl;
            cur[4 * t + 1] = excl + p1;
            cur[4 * t + 2] = excl + p2;
            cur[4 * t + 3] = excl + p3;
        }
        __syncthreads();
        if (t < NPG) {
            const int pos = atomicAdd(&cur[min(degI[t], 255)], 1);
            ord[pos] = (ushort)t;
        }
        __syncthreads();
    }

    // ---------------- Layer 1: y1 accumulated in LDS (F cols 64..95); x chunks staged in cols 0..31 ----------------
    {
        const int j = t & 31, nb = t >> 5;
        #pragma unroll 1
        for (int c = 0; c < 4; ++c) {
            for (int i = t; i < 2048; i += 1024) {
                const int n = i >> 3, q2 = i & 7;
                const int gn = g * NPG + n;
                const int j0 = c * 32 + q2 * 4;
                float4 v;
                if (j0 < 64)      v = *(const float4*)(ndata    + (size_t)node_id[gn] * 64 + j0);
                else if (j0 < 96) v = *(const float4*)(node_emb + (size_t)feats[gn] * 32 + (j0 - 64));
                else              v = *(const float4*)(node_emb + (size_t)(NATTR + node_id[gn]) * 32 + (j0 - 96));
                const float sc = ns[n];
                float4 o; o.x = v.x * sc; o.y = v.y * sc; o.z = v.z * sc; o.w = v.w * sc;
                *(float4*)(F + n * 100 + q2 * 4) = o;          // cols 0..31
            }
            __syncthreads();
            float wc[32];
            #pragma unroll
            for (int d = 0; d < 32; ++d) wc[d] = W0[(c * 32 + d) * 32 + j];
            #pragma unroll
            for (int i2 = 0; i2 < 8; ++i2) {
                const int n = nb * 8 + i2;
                const float4* ar = (const float4*)(F + n * 100);
                float a = 0.f;
                #pragma unroll
                for (int d8 = 0; d8 < 8; ++d8) {
                    const float4 av = ar[d8];
                    a = fmaf(av.x, wc[4 * d8 + 0], a);
                    a = fmaf(av.y, wc[4 * d8 + 1], a);
                    a = fmaf(av.z, wc[4 * d8 + 2], a);
                    a = fmaf(av.w, wc[4 * d8 + 3], a);
                }
                if (c == 0) F[n * 100 + 64 + j]  = a;          // LDS accumulator: no acc[8] regs
                else        F[n * 100 + 64 + j] += a;
            }
            __syncthreads();
        }
    }

    // ---------------- Layers 1..3: aggregate; NO register state pinned across phases ----------------
    // !LAST: h -> F cols BOFF pre-barrier (disjoint from Y); read back post-barrier for Y=h*ns; matvec.
    // LAST : h kept in regs across ONE barrier, then written to cols 64..95 in place.
    #define LAYER_STEP(BOFF, WNEXT, LAST)                                              \
    {                                                                                  \
        const int q = t & 7, g3 = (t >> 3) & 7, wvv = t >> 6;                          \
        const int n0 = ord[wvv * 8 + g3];                                              \
        const int n1 = ord[(31 - wvv) * 8 + g3];                                       \
        float4 hv0 = {0.f, 0.f, 0.f, 0.f}, hv1 = {0.f, 0.f, 0.f, 0.f};                 \
        {                                                                              \
            const float4 h = agg_node(sE, rowS[n0], rowS[n0 + 1], F, q,                \
                                      nd[n0], Bs, BOFF);                               \
            float m = fmaxf(fmaxf(h.x, h.y), fmaxf(h.z, h.w));                         \
            m = fmaxf(m, __shfl_xor(m, 1, 64));                                        \
            m = fmaxf(m, __shfl_xor(m, 2, 64));                                        \
            m = fmaxf(m, __shfl_xor(m, 4, 64));                                        \
            if (q == 0) keys[n0] = fmaxf(keys[n0], m);                                 \
            if (!(LAST)) *(float4*)(F + n0 * 100 + (BOFF) + q * 4) = h;                \
            else hv0 = h;                                                              \
        }                                                                              \
        {                                                                              \
            const float4 h = agg_node(sE, rowS[n1], rowS[n1 + 1], F, q,                \
                                      nd[n1], Bs, BOFF);                               \
            float m = fmaxf(fmaxf(h.x, h.y), fmaxf(h.z, h.w));                         \
            m = fmaxf(m, __shfl_xor(m, 1, 64));                                        \
            m = fmaxf(m, __shfl_xor(m, 2, 64));                                        \
            m = fmaxf(m, __shfl_xor(m, 4, 64));                                        \
            if (q == 0) keys[n1] = fmaxf(keys[n1], m);                                 \
            if (!(LAST)) *(float4*)(F + n1 * 100 + (BOFF) + q * 4) = h;                \
            else hv1 = h;                                                              \
        }                                                                              \
        __syncthreads();                       /* all agg reads of Y done */           \
        if (!(LAST)) {                                                                 \
            const float s0 = ns[n0], s1 = ns[n1];                                      \
            float4 a = *(const float4*)(F + n0 * 100 + (BOFF) + q * 4);                \
            float4 b = *(const float4*)(F + n1 * 100 + (BOFF) + q * 4);                \
            a.x *= s0; a.y *= s0; a.z *= s0; a.w *= s0;                                \
            b.x *= s1; b.y *= s1; b.z *= s1; b.w *= s1;                                \
            *(float4*)(F + n0 * 100 + 64 + q * 4) = a;                                 \
            *(float4*)(F + n1 * 100 + 64 + q * 4) = b;                                 \
            __syncthreads();                   /* h*ns rows complete */                \
            matvec_inplace(F, WNEXT, t & 31, t >> 5);                                  \
            __syncthreads();                                                           \
        } else {                                                                       \
            *(float4*)(F + n0 * 100 + 64 + q * 4) = hv0;   /* h3 in place */           \
            *(float4*)(F + n1 * 100 + 64 + q * 4) = hv1;                               \
            __syncthreads();                                                           \
        }                                                                              \
    }
    LAYER_STEP(0,  W1, false)
    LAYER_STEP(32, W2, false)
    LAYER_STEP(64, W2, true)
    #undef LAYER_STEP

    // ---------------- Layer 4: y4 = ns * (h3 @ W3) -> col 97; scalar aggregate -> col 96 ----------------
    if (t < NPG) {
        const float4* fr = (const float4*)(F + t * 100 + 64);
        float a = 0.f;
        #pragma unroll
        for (int d8 = 0; d8 < 8; ++d8) {
            const float4 h = fr[d8];
            a = fmaf(h.x, W3[4 * d8 + 0], a);
            a = fmaf(h.y, W3[4 * d8 + 1], a);
            a = fmaf(h.z, W3[4 * d8 + 2], a);
            a = fmaf(h.w, W3[4 * d8 + 3], a);
        }
        F[t * 100 + 97] = a * ns[t];
    }
    __syncthreads();
    {
        const int n4 = ord[t >> 2], p = t & 3;
        const int rs = rowS[n4], re = rowS[n4 + 1];
        double a = 0.0;
        for (int e = rs + p; e < re; e += 4) {
            const uint2 ed = sE[e];
            a += (double)__uint_as_float(ed.x) * (double)F[ed.y * 100 + 97];
        }
        a += __shfl_xor(a, 1, 64);
        a += __shfl_xor(a, 2, 64);
        if (p == 0) {
            const float h = tanhf((float)(a * (double)nd[n4]) + Bs[96]);
            F[n4 * 100 + 96] = h;              // col 96 disjoint from col-97 reads
            keys[n4] = fmaxf(keys[n4], h);
        }
    }
    __syncthreads();

    // ---------------- head: top-30 -> in-place sort of selected rows -> CNN ----------------
    if (t < 64) {
        // wave 0: top-30, jax.lax.top_k tie semantics (desc value, asc index)
        float kv0 = keys[lane * 4 + 0], kv1 = keys[lane * 4 + 1];
        float kv2 = keys[lane * 4 + 2], kv3 = keys[lane * 4 + 3];
        for (int it = 0; it < 30; ++it) {
            float bv = kv0; int bi = lane * 4;
            if (kv1 > bv) { bv = kv1; bi = lane * 4 + 1; }
            if (kv2 > bv) { bv = kv2; bi = lane * 4 + 2; }
            if (kv3 > bv) { bv = kv3; bi = lane * 4 + 3; }
            #pragma unroll
            for (int off = 1; off <= 32; off <<= 1) {
                const float ov = __shfl_xor(bv, off, 64);
                const int   oi = __shfl_xor(bi, off, 64);
                if (ov > bv || (ov == bv && oi < bi)) { bv = ov; bi = oi; }
            }
            if (lane == 0) selI[it] = bi;
            if ((bi >> 2) == lane) {
                const int r = bi & 3;
                if (r == 0)      kv0 = -INFINITY;
                else if (r == 1) kv1 = -INFINITY;
                else if (r == 2) kv2 = -INFINITY;
                else             kv3 = -INFINITY;
            }
        }
    } else {
        for (int i = t - 64; i < 1552; i += 960) c1wS[i] = c1w[i];
        for (int i = t - 64; i < 2560; i += 960) c2wS[i] = c2w[i];
    }
    __syncthreads();

    // bitonic-128 sort (ascending) of the 30 selected rows, in place in F
    for (int k = wv; k < 30; k += 16) {
        float* fr = F + selI[k] * 100;
        float v0 = fr[lane];
        float v1 = (lane < 33) ? fr[64 + lane] : INFINITY;
        for (int kk = 2; kk <= 128; kk <<= 1) {
            for (int jj = kk >> 1; jj > 0; jj >>= 1) {
                if (jj == 64) {
                    const float lo = fminf(v0, v1), hi = fmaxf(v0, v1);
                    v0 = lo; v1 = hi;
                } else {
                    const float p0 = __shfl_xor(v0, jj, 64);
                    const float p1 = __shfl_xor(v1, jj, 64);
                    const bool up   = ((lane & jj) == 0);
                    const bool asc0 = (kk == 128) ? true : ((lane & kk) == 0);
                    const bool asc1 = (kk == 128) ? true : (((64 + lane) & kk) == 0);
                    v0 = (up == asc0) ? fminf(v0, p0) : fmaxf(v0, p0);
                    v1 = (up == asc1) ? fminf(v1, p1) : fmaxf(v1, p1);
                }
            }
        }
        fr[lane] = v0;
        if (lane < 33) fr[64 + lane] = v1;
    }
    __syncthreads();

    // conv1 (16 ch, kernel 97, stride 97) + relu
    if (t < 480) {
        const int k = t >> 4, c = t & 15;
        const float* row  = F + selI[k] * 100;
        const float* wrow = c1wS + c * 97;
        float acc = c1b[c];
        for (int d = 0; d < 97; ++d) acc = fmaf(row[d], wrow[d], acc);
        L1[k * 16 + c] = fmaxf(acc, 0.f);
    }
    __syncthreads();
    if (t < 240) {
        const int c = t / 15, tt = t % 15;
        Q[c * 15 + tt] = fmaxf(L1[(2 * tt) * 16 + c], L1[(2 * tt + 1) * 16 + c]);
    }
    __syncthreads();
    if (t < 352) {
        const int o = t / 11, tt = t % 11;
        const float* wo = c2wS + o * 80;
        float acc = c2b[o];
        #pragma unroll
        for (int c = 0; c < 16; ++c)
            #pragma unroll
            for (int jj = 0; jj < 5; ++jj)
                acc = fmaf(Q[c * 15 + tt + jj], wo[c * 5 + jj], acc);
        Rr[o * 11 + tt] = fmaxf(acc, 0.f);
    }
    __syncthreads();
    if (t < 128) {
        float acc = f1b[t];
        const float* wr = f1w + t * 352;
        for (int i = 0; i < 352; ++i) acc = fmaf(Rr[i], wr[i], acc);
        Ff[t] = fmaxf(acc, 0.f);
    }
    __syncthreads();
    if (t < 64) {
        float acc = Ff[lane] * f2w[lane] + Ff[lane + 64] * f2w[lane + 64];
        #pragma unroll
        for (int off = 1; off <= 32; off <<= 1) acc += __shfl_xor(acc, off, 64);
        if (lane == 0) out[g] = acc + f2b[0];
    }
}

extern "C" void kernel_launch(void* const* d_in, const int* in_sizes, int n_in,
                              void* d_out, int out_size, void* d_ws, size_t ws_size,
                              hipStream_t stream)
{
    const int*   feats    = (const int*)d_in[0];
    const int*   node_id  = (const int*)d_in[1];
    const int*   edge_id  = (const int*)d_in[2];
    const int*   src      = (const int*)d_in[3];
    const int*   dst      = (const int*)d_in[4];
    const float* ndata    = (const float*)d_in[5];
    const float* edata    = (const float*)d_in[6];
    const float* node_emb = (const float*)d_in[7];
    const float* W0 = (const float*)d_in[8];
    const float* b0 = (const float*)d_in[9];
    const float* W1 = (const float*)d_in[10];
    const float* b1 = (const float*)d_in[11];
    const float* W2 = (const float*)d_in[12];
    const float* b2 = (const float*)d_in[13];
    const float* W3 = (const float*)d_in[14];
    const float* b3 = (const float*)d_in[15];
    const float* c1w = (const float*)d_in[16];
    const float* c1b = (const float*)d_in[17];
    const float* c2w = (const float*)d_in[18];
    const float* c2b = (const float*)d_in[19];
    const float* f1w = (const float*)d_in[20];
    const float* f1b = (const float*)d_in[21];
    const float* f2w = (const float*)d_in[22];
    const float* f2b = (const float*)d_in[23];

    (void)hipFuncSetAttribute((const void*)dgcnn_fused,
                              hipFuncAttributeMaxDynamicSharedMemorySize, A_TOTAL);

    dgcnn_fused<<<NGRAPH, 1024, A_TOTAL, stream>>>(feats, node_id, edge_id, src, dst,
                                                   ndata, edata, node_emb,
                                                   W0, b0, W1, b1, W2, b2, W3, b3,
                                                   c1w, c1b, c2w, c2b,
                                                   f1w, f1b, f2w, f2b,
                                                   (float*)d_out);
}